// Round 14
// baseline (599.661 us; speedup 1.0000x reference)
//
#include <hip/hip_runtime.h>
#include <hip/hip_bf16.h>
#include <math.h>

typedef __hip_bfloat16 bf16;
typedef __attribute__((ext_vector_type(8))) short short8;
typedef __attribute__((ext_vector_type(4))) float f32x4;

#define D_MODEL   2048
#define D_INNER   4096
#define NHEADS    64
#define DSTATE    64
#define D_XB      1024
#define XB_HEADS  16
#define REP       4
#define DCONV     4
#define CHUNK     128
#define SEQLEN    4096
#define NCHUNK    (SEQLEN / CHUNK)                 // 32
#define D_IN_PROJ (2*D_INNER + 2*D_XB + NHEADS)    // 10304
#define NPAD      10496                            // 82*128
#define CONV_DIM  (D_INNER + 2*D_XB)               // 6144
#define EPS       1e-5f
#define LOG2E     1.44269504f

// ---------------- workspace layout (bytes) ----------------
#define Z_BYTES    ((size_t)SEQLEN * D_INNER * 2)                   // 33,554,432
#define RAW_BYTES  ((size_t)SEQLEN * CONV_DIM * 2)                  // 50,331,648
#define DTP_BYTES  ((size_t)SEQLEN * NHEADS * 4)                    //  1,048,576
#define CDEC_BYTES ((size_t)NCHUNK * NHEADS * 4)                    //      8,192
#define CONV_BYTES ((size_t)SEQLEN * CONV_DIM * 2)                  // 50,331,648
#define S_BYTES    ((size_t)NCHUNK * NHEADS * DSTATE * DSTATE * 4)  // 33,554,432
#define U_BYTES    ((size_t)SEQLEN * D_MODEL * 2)                   // 16,777,216
#define RREG_BYTES (CONV_BYTES + S_BYTES)                           // 83,886,080 (>= U+WinT)
#define WS_BYTES   (Z_BYTES + RAW_BYTES + DTP_BYTES + CDEC_BYTES + RREG_BYTES)

__device__ __forceinline__ short f2bf(float f) {
  bf16 h = __float2bfloat16(f);
  return *reinterpret_cast<short*>(&h);
}
__device__ __forceinline__ float bf2f(short s) {
  unsigned int u = ((unsigned int)(unsigned short)s) << 16;
  union { unsigned int u; float f; } c; c.u = u; return c.f;
}

__device__ __forceinline__ void gload_lds16(const void* g, void* l) {
  typedef __attribute__((address_space(1))) const unsigned int guint;
  typedef __attribute__((address_space(3))) unsigned int luint;
  __builtin_amdgcn_global_load_lds((guint*)g, (luint*)l, 16, 0, 0);
}

// swizzled LDS addressing helpers (involutions)
__device__ __forceinline__ char* swz128p(char* b, int r, int c) {
  int o = r * 128 + c * 2; o ^= (r & 7) << 4; return b + o;
}
__device__ __forceinline__ const char* swz128p(const char* b, int r, int c) {
  int o = r * 128 + c * 2; o ^= (r & 7) << 4; return b + o;
}
__device__ __forceinline__ char* swz256p(char* b, int r, int c) {
  int o = r * 256 + c * 2; o ^= (r & 15) << 4; return b + o;
}
__device__ __forceinline__ const char* swz256p(const char* b, int r, int c) {
  int o = r * 256 + c * 2; o ^= (r & 15) << 4; return b + o;
}

// ---------------- diagnostic fill ----------------
__global__ void fill_kernel(float* p, size_t n, float v) {
  size_t i = (size_t)blockIdx.x * blockDim.x + threadIdx.x;
  if (i < n) p[i] = v;
}

// ---------------- cast f32 -> bf16 ----------------
__global__ __launch_bounds__(256) void cast_f32_bf16(
    const float* __restrict__ in, short* __restrict__ out, size_t n4) {
  size_t i = (size_t)blockIdx.x * 256 + threadIdx.x;
  if (i >= n4) return;
  float4 v = ((const float4*)in)[i];
  short4 o;
  o.x = f2bf(v.x); o.y = f2bf(v.y); o.z = f2bf(v.z); o.w = f2bf(v.w);
  ((short4*)out)[i] = o;
}

// ---------------- transpose + cast v2: in[R][C] f32 -> out[Cpad][R] bf16 ----------
__global__ __launch_bounds__(256) void transpose_cast(
    const float* __restrict__ in, short* __restrict__ out, int R, int C) {
  __shared__ float tile[32][130];
  const int r0 = blockIdx.y * 128;
  const int c0 = blockIdx.x * 32;
  const int tid = threadIdx.x;
  {
    int cq = tid & 7;
    int rbase = tid >> 3;
    bool valid = (c0 + cq * 4) < C;
#pragma unroll
    for (int i = 0; i < 4; ++i) {
      int r = rbase + i * 32;
      float4 v = make_float4(0.f, 0.f, 0.f, 0.f);
      if (valid) v = *(const float4*)(in + (size_t)(r0 + r) * C + c0 + cq * 4);
      tile[cq * 4 + 0][r] = v.x;
      tile[cq * 4 + 1][r] = v.y;
      tile[cq * 4 + 2][r] = v.z;
      tile[cq * 4 + 3][r] = v.w;
    }
  }
  __syncthreads();
  {
    int rq = tid & 31;
    int cbase = tid >> 5;
#pragma unroll
    for (int i = 0; i < 4; ++i) {
      int c = cbase + i * 8;
      short4 o;
      o.x = f2bf(tile[c][rq * 4 + 0]);
      o.y = f2bf(tile[c][rq * 4 + 1]);
      o.z = f2bf(tile[c][rq * 4 + 2]);
      o.w = f2bf(tile[c][rq * 4 + 3]);
      *(short4*)(out + (size_t)(c0 + c) * R + r0 + rq * 4) = o;
    }
  }
}

// ================== BM x BN GEMM core, 4-phase/K-tile, counted vmcnt ==============
// Generalized over (BM, BN, THREADS, NWN). Both GEMMs now use <128,128,256,2>:
// 64KB LDS -> 2 blocks/CU co-residency; independent barriers hide drains.

template<int NLOADS, int THREADS>
__device__ __forceinline__ void stage_half(const char* gtile, int rowbytes,
                                           char* ldst, int tid) {
#pragma unroll
  for (int i = 0; i < NLOADS; ++i) {
    int cid = i * THREADS + tid;
    int r = cid >> 2;                 // 64B rows: 4 chunks/row
    int pos = ((cid & 3) * 16) ^ (((r >> 1) & 3) << 4);
    gload_lds16(gtile + (size_t)r * rowbytes + pos, ldst + cid * 16);
  }
}

__device__ __forceinline__ void bar_only() {
  __builtin_amdgcn_sched_barrier(0);
  __builtin_amdgcn_s_barrier();
  __builtin_amdgcn_sched_barrier(0);
}

template<int N>
__device__ __forceinline__ void wait_bar() {
  __builtin_amdgcn_sched_barrier(0);
  if constexpr (N == 0) asm volatile("s_waitcnt vmcnt(0)" ::: "memory");
  else if constexpr (N == 3) asm volatile("s_waitcnt vmcnt(3)" ::: "memory");
  else if constexpr (N == 4) asm volatile("s_waitcnt vmcnt(4)" ::: "memory");
  __builtin_amdgcn_s_barrier();
  __builtin_amdgcn_sched_barrier(0);
}

// one quadrant phase: ds_read a[MF] (+b[4] if mh==0), barrier, lgkmcnt, MFMA
template<int BM>
__device__ __forceinline__ void quad_phase(const char* ldsA_kh, const char* ldsB_kh,
    int mh, int wm, int wn, int fr, int kqb, short8 (&b)[4], bool load_b,
    f32x4 (&acc)[BM / 32][4]) {
  constexpr int MF = BM / 64;   // a-frags per phase
  short8 a[MF];
#pragma unroll
  for (int m = 0; m < MF; ++m) {
    int r = wm * (BM / 2) + mh * (BM / 4) + m * 16 + fr;
    a[m] = *(const short8*)(ldsA_kh + r * 64 + (kqb ^ (((r >> 1) & 3) << 4)));
  }
  if (load_b) {
#pragma unroll
    for (int n = 0; n < 4; ++n) {
      int r = wn * 64 + n * 16 + fr;
      b[n] = *(const short8*)(ldsB_kh + r * 64 + (kqb ^ (((r >> 1) & 3) << 4)));
    }
  }
  __builtin_amdgcn_sched_barrier(0);
  __builtin_amdgcn_s_barrier();
  asm volatile("s_waitcnt lgkmcnt(0)" ::: "memory");
  __builtin_amdgcn_sched_barrier(0);
  __builtin_amdgcn_s_setprio(1);
#pragma unroll
  for (int m = 0; m < MF; ++m)
#pragma unroll
    for (int n = 0; n < 4; ++n)
      acc[mh * MF + m][n] = __builtin_amdgcn_mfma_f32_16x16x32_bf16(a[m], b[n], acc[mh * MF + m][n], 0, 0, 0);
  __builtin_amdgcn_s_setprio(0);
}

template<int BM, int BN, int THREADS, int NWN>
__device__ __forceinline__ void gemm_core(const short* A, const short* Bt, int K,
    int rowBase, int colBase, char* lds, f32x4 (&acc)[BM / 32][4]) {
  constexpr int SA = BM * 64;               // A k-half bytes
  constexpr int SB = BN * 64;               // B k-half bytes
  constexpr int NLA = SA / 16 / THREADS;    // A loads/thread per half
  constexpr int NLB = SB / 16 / THREADS;    // B loads/thread per half
  constexpr int W = NLA + NLB;              // counted vmcnt
  const int tid = threadIdx.x, lane = tid & 63;
  const int w = tid >> 6, wm = w / NWN, wn = w % NWN;
  const int fr = lane & 15, kqb = (lane >> 4) * 16;
  const int NT = K >> 6;
  const int rb = K * 2;
  char* ldsA = lds;
  char* ldsB = lds + 4 * SA;
  const char* Ag = (const char*)(A + (size_t)rowBase * K);
  const char* Bg = (const char*)(Bt + (size_t)colBase * K);
  // prologue: stage tile 0 fully; wait kh0 (kh1 stays in flight)
  stage_half<NLA, THREADS>(Ag, rb, ldsA, tid);
  stage_half<NLB, THREADS>(Bg, rb, ldsB, tid);
  stage_half<NLA, THREADS>(Ag + 64, rb, ldsA + SA, tid);
  stage_half<NLB, THREADS>(Bg + 64, rb, ldsB + SB, tid);
  wait_bar<W>();
  for (int t = 0; t < NT; ++t) {
    const int cbA = (t & 1) * 2 * SA, nbA = ((t + 1) & 1) * 2 * SA;
    const int cbB = (t & 1) * 2 * SB, nbB = ((t + 1) & 1) * 2 * SB;
    const size_t ko = (size_t)(t + 1) * 128;
    const bool more = (t + 1 < NT);
    short8 b0[4], b1[4];
    // ph0: stage A-kh0(t+1); quadrant (mh0, ks0)
    if (more) stage_half<NLA, THREADS>(Ag + ko, rb, ldsA + nbA, tid);
    quad_phase<BM>(ldsA + cbA, ldsB + cbB, 0, wm, wn, fr, kqb, b0, true, acc);
    bar_only();
    // ph1: stage B-kh0(t+1); quadrant (mh1, ks0); wait kh1(t)
    if (more) stage_half<NLB, THREADS>(Bg + ko, rb, ldsB + nbB, tid);
    quad_phase<BM>(ldsA + cbA, ldsB + cbB, 1, wm, wn, fr, kqb, b0, false, acc);
    if (more) { wait_bar<W>(); } else { wait_bar<0>(); }
    // ph2: stage A-kh1(t+1); quadrant (mh0, ks1)
    if (more) stage_half<NLA, THREADS>(Ag + ko + 64, rb, ldsA + nbA + SA, tid);
    quad_phase<BM>(ldsA + cbA + SA, ldsB + cbB + SB, 0, wm, wn, fr, kqb, b1, true, acc);
    bar_only();
    // ph3: stage B-kh1(t+1); quadrant (mh1, ks1); wait kh0(t+1)
    if (more) stage_half<NLB, THREADS>(Bg + ko + 64, rb, ldsB + nbB + SB, tid);
    quad_phase<BM>(ldsA + cbA + SA, ldsB + cbB + SB, 1, wm, wn, fr, kqb, b1, false, acc);
    if (more) { wait_bar<W>(); } else { wait_bar<0>(); }
  }
}

// ---------------- GEMM1: zxbcdt = u @ W_in (128x128, 2 blocks/CU, 2624 grid) -----
__global__ __launch_bounds__(256) void gemm1_8ph(
    const short* __restrict__ A, const short* __restrict__ Bt,
    bf16* __restrict__ z, bf16* __restrict__ raw, float* __restrict__ dtraw) {
  __shared__ __align__(16) char lds[65536];
  f32x4 acc[4][4] = {};
  // 2624 blocks = 8 XCD x 328; col-major within XCD chunk (B-panel L2 reuse)
  const int bid = blockIdx.x;
  const int s = (bid & 7) * 328 + (bid >> 3);
  const int rowBase = (s & 31) * 128;
  const int colBase = (s >> 5) * 128;
  gemm_core<128, 128, 256, 2>(A, Bt, D_MODEL, rowBase, colBase, lds, acc);
  const int lane = threadIdx.x & 63, w = threadIdx.x >> 6;
  const int wm = w >> 1, wn = w & 1;
  const int fr = lane & 15, kq = lane >> 4;
  const int r0 = rowBase + wm * 64 + kq * 4;
  const int c0 = colBase + wn * 64 + fr;
#pragma unroll
  for (int M = 0; M < 4; ++M)
#pragma unroll
    for (int n = 0; n < 4; ++n) {
      int col = c0 + n * 16;
#pragma unroll
      for (int j = 0; j < 4; ++j) {
        int row = r0 + M * 16 + j;
        float v = acc[M][n][j];
        if (col < D_INNER) {
          z[(size_t)row * D_INNER + col] = __float2bfloat16(v);
        } else if (col < D_INNER + CONV_DIM) {
          raw[(size_t)row * CONV_DIM + (col - D_INNER)] = __float2bfloat16(v);
        } else if (col < D_IN_PROJ) {
          dtraw[(size_t)row * NHEADS + (col - D_INNER - CONV_DIM)] = v;
        }
      }
    }
}

// ---------------- GEMM2: out = normed @ W_out (128x128, 2 blocks/CU, 512 grid) ----
__global__ __launch_bounds__(256) void gemm2_8ph(
    const short* __restrict__ A, const short* __restrict__ Bt,
    float* __restrict__ C) {
  __shared__ __align__(16) char lds[65536];
  f32x4 acc[4][4] = {};
  // 512 blocks = 8 XCD x 64; col-major within XCD chunk
  const int bid = blockIdx.x;
  const int s = (bid & 7) * 64 + (bid >> 3);
  const int rowBase = (s & 31) * 128;
  const int colBase = (s >> 5) * 128;
  gemm_core<128, 128, 256, 2>(A, Bt, D_INNER, rowBase, colBase, lds, acc);
  const int lane = threadIdx.x & 63, w = threadIdx.x >> 6;
  const int wm = w >> 1, wn = w & 1;
  const int fr = lane & 15, kq = lane >> 4;
  const int r0 = rowBase + wm * 64 + kq * 4;
  const int c0 = colBase + wn * 64 + fr;
#pragma unroll
  for (int M = 0; M < 4; ++M)
#pragma unroll
    for (int n = 0; n < 4; ++n) {
      int col = c0 + n * 16;
#pragma unroll
      for (int j = 0; j < 4; ++j)
        C[(size_t)(r0 + M * 16 + j) * D_MODEL + col] = acc[M][n][j];
    }
}

// ---------------- conv1d + SiLU, vectorized (8 channels/thread) ----------------
__global__ __launch_bounds__(256) void conv_silu_kernel(
    const bf16* __restrict__ raw, const float* __restrict__ cw,
    const float* __restrict__ cb, bf16* __restrict__ convout) {
  int idx = blockIdx.x * 256 + threadIdx.x;
  if (idx >= SEQLEN * (CONV_DIM / 8)) return;
  int t = idx / (CONV_DIM / 8);
  int c8 = (idx % (CONV_DIM / 8)) * 8;
  float acc[8];
  float4 w[8];
#pragma unroll
  for (int q = 0; q < 8; ++q) {
    acc[q] = cb[c8 + q];
    w[q] = ((const float4*)cw)[c8 + q];
  }
#pragma unroll
  for (int k = 0; k < DCONV; ++k) {
    int tt = t - (DCONV - 1) + k;
    if (tt < 0) continue;
    short8 v = *(const short8*)((const short*)raw + (size_t)tt * CONV_DIM + c8);
#pragma unroll
    for (int q = 0; q < 8; ++q)
      acc[q] += bf2f(v[q]) * ((const float*)&w[q])[k];
  }
  short8 o;
#pragma unroll
  for (int q = 0; q < 8; ++q) {
    float s = acc[q] / (1.f + expf(-acc[q]));
    o[q] = f2bf(s);
  }
  *(short8*)((short*)convout + (size_t)t * CONV_DIM + c8) = o;
}

// ---------------- dt softplus ----------------
__global__ __launch_bounds__(256) void dt_softplus_kernel(
    float* __restrict__ dtp, const float* __restrict__ dt_bias) {
  int idx = blockIdx.x * blockDim.x + threadIdx.x;
  if (idx >= SEQLEN * NHEADS) return;
  int h = idx & (NHEADS - 1);
  float x = dtp[idx] + dt_bias[h];
  dtp[idx] = (x > 20.f) ? x : log1pf(expf(x));
}

// ---------------- SSD pass A (MFMA): ST[p][n] = sum_j X[j,p]*w_j*B[j,n] ----------------
__global__ __launch_bounds__(256) void ssd_passA(
    const bf16* __restrict__ conv, const float* __restrict__ dtp,
    const float* __restrict__ A_log, short* __restrict__ Sbuf,
    float* __restrict__ cdec) {
  __shared__ __align__(16) char sBn[16384];
  __shared__ __align__(16) char sXn[16384];
  __shared__ __align__(16) char sBT[16384];
  __shared__ __align__(16) char sXT[16384];
  __shared__ float sdt[CHUNK], scum2[CHUNK], sw[CHUNK];
  const int chunk = blockIdx.x, h = blockIdx.y, g = h >> 2;
  const int tid = threadIdx.x, lane = tid & 63, wid = tid >> 6;
  const int t0 = chunk * CHUNK;
  const int fr = lane & 15, kq = lane >> 4;
  {
    const short* cg = (const short*)conv;
#pragma unroll
    for (int it = 0; it < 4; ++it) {
      int cid = tid + it * 256;
      int r = cid >> 3, c8 = (cid & 7) * 8;
      size_t rowoff = (size_t)(t0 + r) * CONV_DIM;
      *(short8*)swz128p(sBn, r, c8) = *(const short8*)(cg + rowoff + D_XB + g * 64 + c8);
      *(short8*)swz128p(sXn, r, c8) = *(const short8*)(cg + rowoff + g * 64 + c8);
    }
    if (tid < CHUNK) sdt[tid] = dtp[(size_t)(t0 + tid) * NHEADS + h];
  }
  __syncthreads();
  if (tid < CHUNK) {
    float Ah2 = -expf(A_log[h]) * LOG2E;
    float s_all = 0.f, s_le = 0.f;
    for (int i = 0; i < CHUNK; ++i) {
      float v = sdt[i] * Ah2;
      s_all += v;
      if (i <= tid) s_le += v;
    }
    scum2[tid] = s_le;
    sw[tid] = exp2f(s_all - s_le) * sdt[tid];
    if (tid == 0) cdec[chunk * NHEADS + h] = exp2f(s_all);
  }
  __syncthreads();
  {
    const int col = tid & 63, jb = (tid >> 6) * 32;
#pragma unroll
    for (int it = 0; it < 32; ++it) {
      int j = jb + it;
      *(short*)swz256p(sBT, col, j) = *(const short*)swz128p(sBn, j, col);
      float xv = bf2f(*(const short*)swz128p(sXn, j, col));
      *(short*)swz256p(sXT, col, j) = f2bf(xv * sw[j]);
    }
  }
  __syncthreads();
  f32x4 acc[4] = {};
#pragma unroll
  for (int ks = 0; ks < 4; ++ks) {
    short8 a = *(const short8*)swz256p(sXT, wid * 16 + fr, ks * 32 + kq * 8);
    short8 b[4];
#pragma unroll
    for (int n = 0; n < 4; ++n) b[n] = *(const short8*)swz256p(sBT, n * 16 + fr, ks * 32 + kq * 8);
#pragma unroll
    for (int n = 0; n < 4; ++n)
      acc[n] = __builtin_amdgcn_mfma_f32_16x16x32_bf16(a, b[n], acc[n], 0, 0, 0);
  }
  short* So = Sbuf + ((size_t)(chunk * NHEADS + h)) * (DSTATE * DSTATE);
#pragma unroll
  for (int n = 0; n < 4; ++n)
#pragma unroll
    for (int jj = 0; jj < 4; ++jj) {
      int p = wid * 16 + kq * 4 + jj;
      int nc = n * 16 + fr;
      So[p * 64 + nc] = f2bf(acc[n][jj]);
    }
}

// ---------------- SSD pass B: recurrence, in-place S->Hprev (bf16) ----------------
__global__ __launch_bounds__(256) void ssd_passB(
    short* __restrict__ Sbuf, const float* __restrict__ cdec) {
  const int h = blockIdx.x;
  const int base = blockIdx.y * 1024 + threadIdx.x * 4;
  float H[4] = {};
  for (int c = 0; c < NCHUNK; ++c) {
    short4* Sc = (short4*)(Sbuf + ((size_t)(c * NHEADS + h)) * (DSTATE * DSTATE) + base);
    short4 v = *Sc;
    short4 o;
    o.x = f2bf(H[0]); o.y = f2bf(H[1]); o.z = f2bf(H[2]); o.w = f2bf(H[3]);
    *Sc = o;
    float dec = cdec[c * NHEADS + h];
    H[0] = dec * H[0] + bf2f(v.x);
    H[1] = dec * H[1] + bf2f(v.y);
    H[2] = dec * H[2] + bf2f(v.z);
    H[3] = dec * H[3] + bf2f(v.w);
  }
}

// ---------------- SSD pass C (MFMA) ----------------
__global__ __launch_bounds__(256) void ssd_passC(
    const bf16* __restrict__ z, const bf16* __restrict__ conv,
    const float* __restrict__ dtp, const float* __restrict__ A_log,
    const float* __restrict__ Dv, const float* __restrict__ nw,
    const short* __restrict__ Hprev, bf16* __restrict__ normed) {
  __shared__ __align__(16) char sC[16384];
  __shared__ __align__(16) char sBX[16384];
  __shared__ __align__(16) char sP[32768];
  __shared__ __align__(16) char sST[8192];
  __shared__ float sdt[CHUNK], scum2[CHUNK];
  const int chunk = blockIdx.x, h = blockIdx.y, g = h >> 2;
  const int tid = threadIdx.x, lane = tid & 63, wid = tid >> 6;
  const int t0 = chunk * CHUNK;
  const int fr = lane & 15, kq = lane >> 4;
  const int wi = wid * 32;
  {
    const short* cg = (const short*)conv;
#pragma unroll
    for (int it = 0; it < 4; ++it) {
      int cid = tid + it * 256;
      int r = cid >> 3, c8 = (cid & 7) * 8;
      size_t rowoff = (size_t)(t0 + r) * CONV_DIM;
      *(short8*)swz128p(sC, r, c8) = *(const short8*)(cg + rowoff + 2 * D_XB + h * 64 + c8);
      *(short8*)swz128p(sBX, r, c8) = *(const short8*)(cg + rowoff + D_XB + g * 64 + c8);
      *(short8*)swz128p(sP + 16384, r, c8) = *(const short8*)(cg + rowoff + g * 64 + c8);
    }
    if (tid < CHUNK) sdt[tid] = dtp[(size_t)(t0 + tid) * NHEADS + h];
  }
  __syncthreads();
  if (tid < CHUNK) {
    float Ah2 = -expf(A_log[h]) * LOG2E;
    float s_le = 0.f;
    for (int i = 0; i <= tid; ++i) s_le += sdt[i] * Ah2;
    scum2[tid] = s_le;
  }
  __syncthreads();
  f32x4 accG[2][8] = {};
#pragma unroll
  for (int ks = 0; ks < 2; ++ks) {
    short8 a[2], b[8];
#pragma unroll
    for (int m = 0; m < 2; ++m)
      a[m] = *(const short8*)swz128p(sC, wi + m * 16 + fr, ks * 32 + kq * 8);
#pragma unroll
    for (int n = 0; n < 8; ++n)
      b[n] = *(const short8*)swz128p(sBX, n * 16 + fr, ks * 32 + kq * 8);
#pragma unroll
    for (int m = 0; m < 2; ++m)
#pragma unroll
      for (int n = 0; n < 8; ++n)
        accG[m][n] = __builtin_amdgcn_mfma_f32_16x16x32_bf16(a[m], b[n], accG[m][n], 0, 0, 0);
  }
  __syncthreads();
  {
    const int p = tid & 63, jb = (tid >> 6) * 32;
#pragma unroll
    for (int it = 0; it < 32; ++it) {
      int j = jb + it;
      *(short*)swz256p(sBX, p, j) = *(const short*)swz128p(sP + 16384, j, p);
    }
    const short* Hp = Hprev + ((size_t)(chunk * NHEADS + h)) * (DSTATE * DSTATE);
#pragma unroll
    for (int it = 0; it < 2; ++it) {
      int cid = tid + it * 256;
      int pr = cid >> 3, c8 = (cid & 7) * 8;
      *(short8*)swz128p(sST, pr, c8) = *(const short8*)(Hp + pr * 64 + c8);
    }
  }
  __syncthreads();
#pragma unroll
  for (int m = 0; m < 2; ++m)
#pragma unroll
    for (int jj = 0; jj < 4; ++jj) {
      int i = wi + m * 16 + kq * 4 + jj;
      float ci = scum2[i];
#pragma unroll
      for (int n = 0; n < 8; ++n) {
        int j = n * 16 + fr;
        float w = (j <= i) ? exp2f(ci - scum2[j]) * sdt[j] : 0.f;
        *(short*)swz256p(sP, i, j) = f2bf(accG[m][n][jj] * w);
      }
    }
  __syncthreads();
  f32x4 acc1[2][4] = {};
#pragma unroll
  for (int ks = 0; ks < 4; ++ks) {
    short8 a[2], b[4];
#pragma unroll
    for (int m = 0; m < 2; ++m)
      a[m] = *(const short8*)swz256p(sP, wi + m * 16 + fr, ks * 32 + kq * 8);
#pragma unroll
    for (int n = 0; n < 4; ++n)
      b[n] = *(const short8*)swz256p(sBX, n * 16 + fr, ks * 32 + kq * 8);
#pragma unroll
    for (int m = 0; m < 2; ++m)
#pragma unroll
      for (int n = 0; n < 4; ++n)
        acc1[m][n] = __builtin_amdgcn_mfma_f32_16x16x32_bf16(a[m], b[n], acc1[m][n], 0, 0, 0);
  }
  f32x4 acc2[2][4] = {};
#pragma unroll
  for (int ks = 0; ks < 2; ++ks) {
    short8 a[2], b[4];
#pragma unroll
    for (int m = 0; m < 2; ++m)
      a[m] = *(const short8*)swz128p(sC, wi + m * 16 + fr, ks * 32 + kq * 8);
#pragma unroll
    for (int n = 0; n < 4; ++n)
      b[n] = *(const short8*)swz128p(sST, n * 16 + fr, ks * 32 + kq * 8);
#pragma unroll
    for (int m = 0; m < 2; ++m)
#pragma unroll
      for (int n = 0; n < 4; ++n)
        acc2[m][n] = __builtin_amdgcn_mfma_f32_16x16x32_bf16(a[m], b[n], acc2[m][n], 0, 0, 0);
  }
  const float Dh = Dv[h];
#pragma unroll
  for (int m = 0; m < 2; ++m)
#pragma unroll
    for (int jj = 0; jj < 4; ++jj) {
      int i = wi + m * 16 + kq * 4 + jj;
      int t = t0 + i;
      float e2 = exp2f(scum2[i]);
      float vs[4];
      float ss = 0.f;
#pragma unroll
      for (int n = 0; n < 4; ++n) {
        int p = n * 16 + fr;
        float xv = bf2f(((const short*)conv)[(size_t)t * CONV_DIM + g * 64 + p]);
        float zv = bf2f(((const short*)z)[(size_t)t * D_INNER + h * 64 + p]);
        float y = acc1[m][n][jj] + e2 * acc2[m][n][jj] + xv * Dh;
        float sz = zv / (1.f + expf(-zv));
        float v = y * sz;
        vs[n] = v;
        ss += v * v;
      }
      ss += __shfl_xor(ss, 1);
      ss += __shfl_xor(ss, 2);
      ss += __shfl_xor(ss, 4);
      ss += __shfl_xor(ss, 8);
      float rinv = rsqrtf(ss * (1.f / 64.f) + EPS);
#pragma unroll
      for (int n = 0; n < 4; ++n) {
        int p = n * 16 + fr;
        ((short*)normed)[(size_t)t * D_INNER + h * 64 + p] = f2bf(vs[n] * rinv * nw[h * 64 + p]);
      }
    }
}

// ---------------- launch ----------------
extern "C" void kernel_launch(void* const* d_in, const int* in_sizes, int n_in,
                              void* d_out, int out_size, void* d_ws, size_t ws_size,
                              hipStream_t stream) {
  const float* u       = (const float*)d_in[0];
  const float* W_in    = (const float*)d_in[1];
  const float* conv_w  = (const float*)d_in[2];
  const float* conv_b  = (const float*)d_in[3];
  const float* dt_bias = (const float*)d_in[4];
  const float* A_log   = (const float*)d_in[5];
  const float* Dv      = (const float*)d_in[6];
  const float* norm_w  = (const float*)d_in[7];
  const float* W_out   = (const float*)d_in[8];
  float* out = (float*)d_out;

  if (ws_size < WS_BYTES) {
    size_t n = (size_t)out_size;
    fill_kernel<<<(n + 255) / 256, 256, 0, stream>>>(out, n, 1000.0f);
    return;
  }

  char* wsb   = (char*)d_ws;
  bf16*  z    = (bf16*)(wsb);
  bf16*  raw  = (bf16*)(wsb + Z_BYTES);
  float* dtp  = (float*)(wsb + Z_BYTES + RAW_BYTES);
  float* cdec = (float*)(wsb + Z_BYTES + RAW_BYTES + DTP_BYTES);
  char*  R    = wsb + Z_BYTES + RAW_BYTES + DTP_BYTES + CDEC_BYTES;
  short* u_bf  = (short*)(R);
  short* WinT  = (short*)(R + U_BYTES);
  bf16*  conv  = (bf16*)(R);
  short* Sbuf  = (short*)(R + CONV_BYTES);
  short* WoutT = (short*)(R);
  bf16*  normed = raw;

  // 0) casts for GEMM1
  cast_f32_bf16<<<(U_BYTES / 8 + 255) / 256, 256, 0, stream>>>(u, u_bf, U_BYTES / 8);
  {
    dim3 grid(NPAD / 32, D_MODEL / 128);
    transpose_cast<<<grid, 256, 0, stream>>>(W_in, WinT, D_MODEL, D_IN_PROJ);
  }
  // 1) GEMM1 (128x128, 2 blocks/CU, 2624 blocks = 5.1 rounds, tail 2.4%)
  gemm1_8ph<<<(NPAD / 128) * (SEQLEN / 128), 256, 0, stream>>>(u_bf, WinT, z, raw, dtp);
  // 2) conv + silu (vectorized)
  conv_silu_kernel<<<(SEQLEN * (CONV_DIM / 8) + 255) / 256, 256, 0, stream>>>(raw, conv_w, conv_b, conv);
  // 3) dt softplus
  dt_softplus_kernel<<<(SEQLEN * NHEADS + 255) / 256, 256, 0, stream>>>(dtp, dt_bias);
  // 4) SSD pass A (MFMA)
  {
    dim3 grid(NCHUNK, NHEADS);
    ssd_passA<<<grid, 256, 0, stream>>>(conv, dtp, A_log, Sbuf, cdec);
  }
  // 5) SSD pass B
  {
    dim3 grid(NHEADS, 4);
    ssd_passB<<<grid, 256, 0, stream>>>(Sbuf, cdec);
  }
  // 6) SSD pass C (MFMA)
  {
    dim3 grid(NCHUNK, NHEADS);
    ssd_passC<<<grid, 256, 0, stream>>>(z, conv, dtp, A_log, Dv, norm_w, Sbuf, normed);
  }
  // 7) W_out transpose + GEMM2 (128x128, 2 blocks/CU, 512 blocks)
  {
    dim3 grid(D_MODEL / 32, D_INNER / 128);
    transpose_cast<<<grid, 256, 0, stream>>>(W_out, WoutT, D_INNER, D_MODEL);
  }
  gemm2_8ph<<<(SEQLEN / 128) * (D_MODEL / 128), 256, 0, stream>>>((const short*)normed, WoutT, out);
}

// Round 16
// 591.010 us; speedup vs baseline: 1.0146x; 1.0146x over previous
//
#include <hip/hip_runtime.h>
#include <hip/hip_bf16.h>
#include <math.h>

typedef __hip_bfloat16 bf16;
typedef __attribute__((ext_vector_type(8))) short short8;
typedef __attribute__((ext_vector_type(4))) float f32x4;

#define D_MODEL   2048
#define D_INNER   4096
#define NHEADS    64
#define DSTATE    64
#define D_XB      1024
#define XB_HEADS  16
#define REP       4
#define DCONV     4
#define CHUNK     128
#define SEQLEN    4096
#define NCHUNK    (SEQLEN / CHUNK)                 // 32
#define D_IN_PROJ (2*D_INNER + 2*D_XB + NHEADS)    // 10304
#define NPAD      10496                            // 41*256
#define CONV_DIM  (D_INNER + 2*D_XB)               // 6144
#define EPS       1e-5f
#define LOG2E     1.44269504f

// ---------------- workspace layout (bytes) ----------------
#define Z_BYTES    ((size_t)SEQLEN * D_INNER * 2)                   // 33,554,432
#define RAW_BYTES  ((size_t)SEQLEN * CONV_DIM * 2)                  // 50,331,648
#define DTP_BYTES  ((size_t)SEQLEN * NHEADS * 4)                    //  1,048,576
#define CDEC_BYTES ((size_t)NCHUNK * NHEADS * 4)                    //      8,192
#define CONV_BYTES ((size_t)SEQLEN * CONV_DIM * 2)                  // region: convx + normed
#define S_BYTES    ((size_t)NCHUNK * NHEADS * DSTATE * DSTATE * 4)
#define U_BYTES    ((size_t)SEQLEN * D_MODEL * 2)                   // 16,777,216
#define RREG_BYTES (CONV_BYTES + S_BYTES)                           // 83,886,080 (>= U+WinT)
#define WS_BYTES   (Z_BYTES + RAW_BYTES + DTP_BYTES + CDEC_BYTES + RREG_BYTES)

__device__ __forceinline__ short f2bf(float f) {
  bf16 h = __float2bfloat16(f);
  return *reinterpret_cast<short*>(&h);
}
__device__ __forceinline__ float bf2f(short s) {
  unsigned int u = ((unsigned int)(unsigned short)s) << 16;
  union { unsigned int u; float f; } c; c.u = u; return c.f;
}

__device__ __forceinline__ void gload_lds16(const void* g, void* l) {
  typedef __attribute__((address_space(1))) const unsigned int guint;
  typedef __attribute__((address_space(3))) unsigned int luint;
  __builtin_amdgcn_global_load_lds((guint*)g, (luint*)l, 16, 0, 0);
}

// swizzled LDS addressing helpers (involutions)
__device__ __forceinline__ char* swz128p(char* b, int r, int c) {
  int o = r * 128 + c * 2; o ^= (r & 7) << 4; return b + o;
}
__device__ __forceinline__ const char* swz128p(const char* b, int r, int c) {
  int o = r * 128 + c * 2; o ^= (r & 7) << 4; return b + o;
}
__device__ __forceinline__ char* swz256p(char* b, int r, int c) {
  int o = r * 256 + c * 2; o ^= (r & 15) << 4; return b + o;
}
__device__ __forceinline__ const char* swz256p(const char* b, int r, int c) {
  int o = r * 256 + c * 2; o ^= (r & 15) << 4; return b + o;
}

// on-the-fly depthwise conv (4-tap) + SiLU for 8 channels -> packed short8
__device__ __forceinline__ short8 conv8(const short* raw, int t, int ch,
                                        const float* cw, const float* cb) {
  float a[8];
  float4 w[8];
#pragma unroll
  for (int q = 0; q < 8; ++q) {
    a[q] = cb[ch + q];
    w[q] = ((const float4*)cw)[ch + q];
  }
#pragma unroll
  for (int k = 0; k < DCONV; ++k) {
    int tt = t - (DCONV - 1) + k;
    if (tt < 0) continue;
    short8 v = *(const short8*)(raw + (size_t)tt * CONV_DIM + ch);
#pragma unroll
    for (int q = 0; q < 8; ++q)
      a[q] += bf2f(v[q]) * ((const float*)&w[q])[k];
  }
  short8 o;
#pragma unroll
  for (int q = 0; q < 8; ++q) {
    float s = a[q] / (1.f + expf(-a[q]));
    o[q] = f2bf(s);
  }
  return o;
}

// ---------------- diagnostic fill ----------------
__global__ void fill_kernel(float* p, size_t n, float v) {
  size_t i = (size_t)blockIdx.x * blockDim.x + threadIdx.x;
  if (i < n) p[i] = v;
}

// ---------------- cast f32 -> bf16 ----------------
__global__ __launch_bounds__(256) void cast_f32_bf16(
    const float* __restrict__ in, short* __restrict__ out, size_t n4) {
  size_t i = (size_t)blockIdx.x * 256 + threadIdx.x;
  if (i >= n4) return;
  float4 v = ((const float4*)in)[i];
  short4 o;
  o.x = f2bf(v.x); o.y = f2bf(v.y); o.z = f2bf(v.z); o.w = f2bf(v.w);
  ((short4*)out)[i] = o;
}

// ---------------- transpose + cast v2: in[R][C] f32 -> out[Cpad][R] bf16 ----------
__global__ __launch_bounds__(256) void transpose_cast(
    const float* __restrict__ in, short* __restrict__ out, int R, int C) {
  __shared__ float tile[32][130];
  const int r0 = blockIdx.y * 128;
  const int c0 = blockIdx.x * 32;
  const int tid = threadIdx.x;
  {
    int cq = tid & 7;
    int rbase = tid >> 3;
    bool valid = (c0 + cq * 4) < C;
#pragma unroll
    for (int i = 0; i < 4; ++i) {
      int r = rbase + i * 32;
      float4 v = make_float4(0.f, 0.f, 0.f, 0.f);
      if (valid) v = *(const float4*)(in + (size_t)(r0 + r) * C + c0 + cq * 4);
      tile[cq * 4 + 0][r] = v.x;
      tile[cq * 4 + 1][r] = v.y;
      tile[cq * 4 + 2][r] = v.z;
      tile[cq * 4 + 3][r] = v.w;
    }
  }
  __syncthreads();
  {
    int rq = tid & 31;
    int cbase = tid >> 5;
#pragma unroll
    for (int i = 0; i < 4; ++i) {
      int c = cbase + i * 8;
      short4 o;
      o.x = f2bf(tile[c][rq * 4 + 0]);
      o.y = f2bf(tile[c][rq * 4 + 1]);
      o.z = f2bf(tile[c][rq * 4 + 2]);
      o.w = f2bf(tile[c][rq * 4 + 3]);
      *(short4*)(out + (size_t)(c0 + c) * R + r0 + rq * 4) = o;
    }
  }
}

// ================== BM x BN GEMM core, 4-phase/K-tile, counted vmcnt ==============

template<int NLOADS, int THREADS>
__device__ __forceinline__ void stage_half(const char* gtile, int rowbytes,
                                           char* ldst, int tid) {
#pragma unroll
  for (int i = 0; i < NLOADS; ++i) {
    int cid = i * THREADS + tid;
    int r = cid >> 2;
    int pos = ((cid & 3) * 16) ^ (((r >> 1) & 3) << 4);
    gload_lds16(gtile + (size_t)r * rowbytes + pos, ldst + cid * 16);
  }
}

__device__ __forceinline__ void bar_only() {
  __builtin_amdgcn_sched_barrier(0);
  __builtin_amdgcn_s_barrier();
  __builtin_amdgcn_sched_barrier(0);
}

template<int N>
__device__ __forceinline__ void wait_bar() {
  __builtin_amdgcn_sched_barrier(0);
  if constexpr (N == 0) asm volatile("s_waitcnt vmcnt(0)" ::: "memory");
  else if constexpr (N == 3) asm volatile("s_waitcnt vmcnt(3)" ::: "memory");
  else if constexpr (N == 4) asm volatile("s_waitcnt vmcnt(4)" ::: "memory");
  __builtin_amdgcn_s_barrier();
  __builtin_amdgcn_sched_barrier(0);
}

template<int BM>
__device__ __forceinline__ void quad_phase(const char* ldsA_kh, const char* ldsB_kh,
    int mh, int wm, int wn, int fr, int kqb, short8 (&b)[4], bool load_b,
    f32x4 (&acc)[BM / 32][4]) {
  constexpr int MF = BM / 64;
  short8 a[MF];
#pragma unroll
  for (int m = 0; m < MF; ++m) {
    int r = wm * (BM / 2) + mh * (BM / 4) + m * 16 + fr;
    a[m] = *(const short8*)(ldsA_kh + r * 64 + (kqb ^ (((r >> 1) & 3) << 4)));
  }
  if (load_b) {
#pragma unroll
    for (int n = 0; n < 4; ++n) {
      int r = wn * 64 + n * 16 + fr;
      b[n] = *(const short8*)(ldsB_kh + r * 64 + (kqb ^ (((r >> 1) & 3) << 4)));
    }
  }
  __builtin_amdgcn_sched_barrier(0);
  __builtin_amdgcn_s_barrier();
  asm volatile("s_waitcnt lgkmcnt(0)" ::: "memory");
  __builtin_amdgcn_sched_barrier(0);
  __builtin_amdgcn_s_setprio(1);
#pragma unroll
  for (int m = 0; m < MF; ++m)
#pragma unroll
    for (int n = 0; n < 4; ++n)
      acc[mh * MF + m][n] = __builtin_amdgcn_mfma_f32_16x16x32_bf16(a[m], b[n], acc[mh * MF + m][n], 0, 0, 0);
  __builtin_amdgcn_s_setprio(0);
}

template<int BM, int BN, int THREADS, int NWN>
__device__ __forceinline__ void gemm_core(const short* A, const short* Bt, int K,
    int rowBase, int colBase, char* lds, f32x4 (&acc)[BM / 32][4]) {
  constexpr int SA = BM * 64;
  constexpr int SB = BN * 64;
  constexpr int NLA = SA / 16 / THREADS;
  constexpr int NLB = SB / 16 / THREADS;
  constexpr int W = NLA + NLB;
  const int tid = threadIdx.x, lane = tid & 63;
  const int w = tid >> 6, wm = w / NWN, wn = w % NWN;
  const int fr = lane & 15, kqb = (lane >> 4) * 16;
  const int NT = K >> 6;
  const int rb = K * 2;
  char* ldsA = lds;
  char* ldsB = lds + 4 * SA;
  const char* Ag = (const char*)(A + (size_t)rowBase * K);
  const char* Bg = (const char*)(Bt + (size_t)colBase * K);
  stage_half<NLA, THREADS>(Ag, rb, ldsA, tid);
  stage_half<NLB, THREADS>(Bg, rb, ldsB, tid);
  stage_half<NLA, THREADS>(Ag + 64, rb, ldsA + SA, tid);
  stage_half<NLB, THREADS>(Bg + 64, rb, ldsB + SB, tid);
  wait_bar<W>();
  for (int t = 0; t < NT; ++t) {
    const int cbA = (t & 1) * 2 * SA, nbA = ((t + 1) & 1) * 2 * SA;
    const int cbB = (t & 1) * 2 * SB, nbB = ((t + 1) & 1) * 2 * SB;
    const size_t ko = (size_t)(t + 1) * 128;
    const bool more = (t + 1 < NT);
    short8 b0[4], b1[4];
    if (more) stage_half<NLA, THREADS>(Ag + ko, rb, ldsA + nbA, tid);
    quad_phase<BM>(ldsA + cbA, ldsB + cbB, 0, wm, wn, fr, kqb, b0, true, acc);
    bar_only();
    if (more) stage_half<NLB, THREADS>(Bg + ko, rb, ldsB + nbB, tid);
    quad_phase<BM>(ldsA + cbA, ldsB + cbB, 1, wm, wn, fr, kqb, b0, false, acc);
    if (more) { wait_bar<W>(); } else { wait_bar<0>(); }
    if (more) stage_half<NLA, THREADS>(Ag + ko + 64, rb, ldsA + nbA + SA, tid);
    quad_phase<BM>(ldsA + cbA + SA, ldsB + cbB + SB, 0, wm, wn, fr, kqb, b1, true, acc);
    bar_only();
    if (more) stage_half<NLB, THREADS>(Bg + ko + 64, rb, ldsB + nbB + SB, tid);
    quad_phase<BM>(ldsA + cbA + SA, ldsB + cbB + SB, 1, wm, wn, fr, kqb, b1, false, acc);
    if (more) { wait_bar<W>(); } else { wait_bar<0>(); }
  }
}

// ---------------- GEMM1: zxbcdt = u @ W_in (256x256, 656 blocks) -----------------
__global__ __launch_bounds__(512) void gemm1_8ph(
    const short* __restrict__ A, const short* __restrict__ Bt,
    bf16* __restrict__ z, bf16* __restrict__ raw, float* __restrict__ dtraw) {
  __shared__ __align__(16) char lds[131072];
  f32x4 acc[8][4] = {};
  const int bid = blockIdx.x;
  const int s = (bid & 7) * 82 + (bid >> 3);
  const int rowBase = (s & 15) * 256;
  const int colBase = (s >> 4) * 256;
  gemm_core<256, 256, 512, 4>(A, Bt, D_MODEL, rowBase, colBase, lds, acc);
  const int lane = threadIdx.x & 63, w = threadIdx.x >> 6;
  const int wm = w >> 2, wn = w & 3;
  const int fr = lane & 15, kq = lane >> 4;
  const int r0 = rowBase + wm * 128 + kq * 4;
  const int c0 = colBase + wn * 64 + fr;
#pragma unroll
  for (int M = 0; M < 8; ++M)
#pragma unroll
    for (int n = 0; n < 4; ++n) {
      int col = c0 + n * 16;
#pragma unroll
      for (int j = 0; j < 4; ++j) {
        int row = r0 + M * 16 + j;
        float v = acc[M][n][j];
        if (col < D_INNER) {
          z[(size_t)row * D_INNER + col] = __float2bfloat16(v);
        } else if (col < D_INNER + CONV_DIM) {
          raw[(size_t)row * CONV_DIM + (col - D_INNER)] = __float2bfloat16(v);
        } else if (col < D_IN_PROJ) {
          dtraw[(size_t)row * NHEADS + (col - D_INNER - CONV_DIM)] = v;
        }
      }
    }
}

// ---------------- GEMM2: out = normed @ W_out (128x128, 2 blocks/CU) -------------
__global__ __launch_bounds__(256) void gemm2_8ph(
    const short* __restrict__ A, const short* __restrict__ Bt,
    float* __restrict__ C) {
  __shared__ __align__(16) char lds[65536];
  f32x4 acc[4][4] = {};
  const int bid = blockIdx.x;
  const int s = (bid & 7) * 64 + (bid >> 3);
  const int rowBase = (s & 31) * 128;
  const int colBase = (s >> 5) * 128;
  gemm_core<128, 128, 256, 2>(A, Bt, D_INNER, rowBase, colBase, lds, acc);
  const int lane = threadIdx.x & 63, w = threadIdx.x >> 6;
  const int wm = w >> 1, wn = w & 1;
  const int fr = lane & 15, kq = lane >> 4;
  const int r0 = rowBase + wm * 64 + kq * 4;
  const int c0 = colBase + wn * 64 + fr;
#pragma unroll
  for (int M = 0; M < 4; ++M)
#pragma unroll
    for (int n = 0; n < 4; ++n) {
      int col = c0 + n * 16;
#pragma unroll
      for (int j = 0; j < 4; ++j)
        C[(size_t)(r0 + M * 16 + j) * D_MODEL + col] = acc[M][n][j];
    }
}

// ---------------- conv1d + SiLU for x channels only (D_XB of CONV_DIM) -----------
__global__ __launch_bounds__(256) void conv_silu_x(
    const bf16* __restrict__ raw, const float* __restrict__ cw,
    const float* __restrict__ cb, bf16* __restrict__ convx) {
  int idx = blockIdx.x * 256 + threadIdx.x;
  if (idx >= SEQLEN * (D_XB / 8)) return;
  int t = idx / (D_XB / 8);
  int c8 = (idx % (D_XB / 8)) * 8;
  short8 o = conv8((const short*)raw, t, c8, cw, cb);
  *(short8*)((short*)convx + (size_t)t * D_XB + c8) = o;
}

// ---------------- dt softplus ----------------
__global__ __launch_bounds__(256) void dt_softplus_kernel(
    float* __restrict__ dtp, const float* __restrict__ dt_bias) {
  int idx = blockIdx.x * blockDim.x + threadIdx.x;
  if (idx >= SEQLEN * NHEADS) return;
  int h = idx & (NHEADS - 1);
  float x = dtp[idx] + dt_bias[h];
  dtp[idx] = (x > 20.f) ? x : log1pf(expf(x));
}

// ---------------- SSD pass A (MFMA, fused conv for B) ----------------
__global__ __launch_bounds__(256) void ssd_passA(
    const bf16* __restrict__ raw, const bf16* __restrict__ convx,
    const float* __restrict__ cw, const float* __restrict__ cb,
    const float* __restrict__ dtp, const float* __restrict__ A_log,
    short* __restrict__ Sbuf, float* __restrict__ cdec) {
  __shared__ __align__(16) char sBn[16384];
  __shared__ __align__(16) char sXn[16384];
  __shared__ __align__(16) char sBT[16384];
  __shared__ __align__(16) char sXT[16384];
  __shared__ float sdt[CHUNK], scum2[CHUNK], sw[CHUNK];
  const int chunk = blockIdx.x, h = blockIdx.y, g = h >> 2;
  const int tid = threadIdx.x, lane = tid & 63, wid = tid >> 6;
  const int t0 = chunk * CHUNK;
  const int fr = lane & 15, kq = lane >> 4;
  {
    const short* cx = (const short*)convx;
#pragma unroll
    for (int it = 0; it < 4; ++it) {
      int cid = tid + it * 256;
      int r = cid >> 3, c8 = (cid & 7) * 8;
      *(short8*)swz128p(sBn, r, c8) =
          conv8((const short*)raw, t0 + r, D_XB + g * 64 + c8, cw, cb);
      *(short8*)swz128p(sXn, r, c8) =
          *(const short8*)(cx + (size_t)(t0 + r) * D_XB + g * 64 + c8);
    }
    if (tid < CHUNK) sdt[tid] = dtp[(size_t)(t0 + tid) * NHEADS + h];
  }
  __syncthreads();
  if (tid < CHUNK) {
    float Ah2 = -expf(A_log[h]) * LOG2E;
    float s_all = 0.f, s_le = 0.f;
    for (int i = 0; i < CHUNK; ++i) {
      float v = sdt[i] * Ah2;
      s_all += v;
      if (i <= tid) s_le += v;
    }
    scum2[tid] = s_le;
    sw[tid] = exp2f(s_all - s_le) * sdt[tid];
    if (tid == 0) cdec[chunk * NHEADS + h] = exp2f(s_all);
  }
  __syncthreads();
  {
    const int col = tid & 63, jb = (tid >> 6) * 32;
#pragma unroll
    for (int it = 0; it < 32; ++it) {
      int j = jb + it;
      *(short*)swz256p(sBT, col, j) = *(const short*)swz128p(sBn, j, col);
      float xv = bf2f(*(const short*)swz128p(sXn, j, col));
      *(short*)swz256p(sXT, col, j) = f2bf(xv * sw[j]);
    }
  }
  __syncthreads();
  f32x4 acc[4] = {};
#pragma unroll
  for (int ks = 0; ks < 4; ++ks) {
    short8 a = *(const short8*)swz256p(sXT, wid * 16 + fr, ks * 32 + kq * 8);
    short8 b[4];
#pragma unroll
    for (int n = 0; n < 4; ++n) b[n] = *(const short8*)swz256p(sBT, n * 16 + fr, ks * 32 + kq * 8);
#pragma unroll
    for (int n = 0; n < 4; ++n)
      acc[n] = __builtin_amdgcn_mfma_f32_16x16x32_bf16(a, b[n], acc[n], 0, 0, 0);
  }
  short* So = Sbuf + ((size_t)(chunk * NHEADS + h)) * (DSTATE * DSTATE);
#pragma unroll
  for (int n = 0; n < 4; ++n)
#pragma unroll
    for (int jj = 0; jj < 4; ++jj) {
      int p = wid * 16 + kq * 4 + jj;
      int nc = n * 16 + fr;
      So[p * 64 + nc] = f2bf(acc[n][jj]);
    }
}

// ---------------- SSD pass B: recurrence, in-place S->Hprev (bf16) ----------------
__global__ __launch_bounds__(256) void ssd_passB(
    short* __restrict__ Sbuf, const float* __restrict__ cdec) {
  const int h = blockIdx.x;
  const int base = blockIdx.y * 1024 + threadIdx.x * 4;
  float H[4] = {};
  for (int c = 0; c < NCHUNK; ++c) {
    short4* Sc = (short4*)(Sbuf + ((size_t)(c * NHEADS + h)) * (DSTATE * DSTATE) + base);
    short4 v = *Sc;
    short4 o;
    o.x = f2bf(H[0]); o.y = f2bf(H[1]); o.z = f2bf(H[2]); o.w = f2bf(H[3]);
    *Sc = o;
    float dec = cdec[c * NHEADS + h];
    H[0] = dec * H[0] + bf2f(v.x);
    H[1] = dec * H[1] + bf2f(v.y);
    H[2] = dec * H[2] + bf2f(v.z);
    H[3] = dec * H[3] + bf2f(v.w);
  }
}

// ---------------- SSD pass C (MFMA, fused conv for B and C) ----------------
__global__ __launch_bounds__(256) void ssd_passC(
    const bf16* __restrict__ z, const bf16* __restrict__ raw,
    const bf16* __restrict__ convx, const float* __restrict__ cw,
    const float* __restrict__ cb, const float* __restrict__ dtp,
    const float* __restrict__ A_log, const float* __restrict__ Dv,
    const float* __restrict__ nw, const short* __restrict__ Hprev,
    bf16* __restrict__ normed) {
  __shared__ __align__(16) char sC[16384];
  __shared__ __align__(16) char sBX[16384];
  __shared__ __align__(16) char sP[32768];
  __shared__ __align__(16) char sST[8192];
  __shared__ float sdt[CHUNK], scum2[CHUNK];
  const int chunk = blockIdx.x, h = blockIdx.y, g = h >> 2;
  const int tid = threadIdx.x, lane = tid & 63, wid = tid >> 6;
  const int t0 = chunk * CHUNK;
  const int fr = lane & 15, kq = lane >> 4;
  const int wi = wid * 32;
  {
    const short* cx = (const short*)convx;
#pragma unroll
    for (int it = 0; it < 4; ++it) {
      int cid = tid + it * 256;
      int r = cid >> 3, c8 = (cid & 7) * 8;
      *(short8*)swz128p(sC, r, c8) =
          conv8((const short*)raw, t0 + r, 2 * D_XB + h * 64 + c8, cw, cb);
      *(short8*)swz128p(sBX, r, c8) =
          conv8((const short*)raw, t0 + r, D_XB + g * 64 + c8, cw, cb);
      *(short8*)swz128p(sP + 16384, r, c8) =
          *(const short8*)(cx + (size_t)(t0 + r) * D_XB + g * 64 + c8);
    }
    if (tid < CHUNK) sdt[tid] = dtp[(size_t)(t0 + tid) * NHEADS + h];
  }
  __syncthreads();
  if (tid < CHUNK) {
    float Ah2 = -expf(A_log[h]) * LOG2E;
    float s_le = 0.f;
    for (int i = 0; i <= tid; ++i) s_le += sdt[i] * Ah2;
    scum2[tid] = s_le;
  }
  __syncthreads();
  f32x4 accG[2][8] = {};
#pragma unroll
  for (int ks = 0; ks < 2; ++ks) {
    short8 a[2], b[8];
#pragma unroll
    for (int m = 0; m < 2; ++m)
      a[m] = *(const short8*)swz128p(sC, wi + m * 16 + fr, ks * 32 + kq * 8);
#pragma unroll
    for (int n = 0; n < 8; ++n)
      b[n] = *(const short8*)swz128p(sBX, n * 16 + fr, ks * 32 + kq * 8);
#pragma unroll
    for (int m = 0; m < 2; ++m)
#pragma unroll
      for (int n = 0; n < 8; ++n)
        accG[m][n] = __builtin_amdgcn_mfma_f32_16x16x32_bf16(a[m], b[n], accG[m][n], 0, 0, 0);
  }
  __syncthreads();
  {
    const int p = tid & 63, jb = (tid >> 6) * 32;
#pragma unroll
    for (int it = 0; it < 32; ++it) {
      int j = jb + it;
      *(short*)swz256p(sBX, p, j) = *(const short*)swz128p(sP + 16384, j, p);
    }
    const short* Hp = Hprev + ((size_t)(chunk * NHEADS + h)) * (DSTATE * DSTATE);
#pragma unroll
    for (int it = 0; it < 2; ++it) {
      int cid = tid + it * 256;
      int pr = cid >> 3, c8 = (cid & 7) * 8;
      *(short8*)swz128p(sST, pr, c8) = *(const short8*)(Hp + pr * 64 + c8);
    }
  }
  __syncthreads();
#pragma unroll
  for (int m = 0; m < 2; ++m)
#pragma unroll
    for (int jj = 0; jj < 4; ++jj) {
      int i = wi + m * 16 + kq * 4 + jj;
      float ci = scum2[i];
#pragma unroll
      for (int n = 0; n < 8; ++n) {
        int j = n * 16 + fr;
        float w = (j <= i) ? exp2f(ci - scum2[j]) * sdt[j] : 0.f;
        *(short*)swz256p(sP, i, j) = f2bf(accG[m][n][jj] * w);
      }
    }
  __syncthreads();
  f32x4 acc1[2][4] = {};
#pragma unroll
  for (int ks = 0; ks < 4; ++ks) {
    short8 a[2], b[4];
#pragma unroll
    for (int m = 0; m < 2; ++m)
      a[m] = *(const short8*)swz256p(sP, wi + m * 16 + fr, ks * 32 + kq * 8);
#pragma unroll
    for (int n = 0; n < 4; ++n)
      b[n] = *(const short8*)swz256p(sBX, n * 16 + fr, ks * 32 + kq * 8);
#pragma unroll
    for (int m = 0; m < 2; ++m)
#pragma unroll
      for (int n = 0; n < 4; ++n)
        acc1[m][n] = __builtin_amdgcn_mfma_f32_16x16x32_bf16(a[m], b[n], acc1[m][n], 0, 0, 0);
  }
  f32x4 acc2[2][4] = {};
#pragma unroll
  for (int ks = 0; ks < 2; ++ks) {
    short8 a[2], b[4];
#pragma unroll
    for (int m = 0; m < 2; ++m)
      a[m] = *(const short8*)swz128p(sC, wi + m * 16 + fr, ks * 32 + kq * 8);
#pragma unroll
    for (int n = 0; n < 4; ++n)
      b[n] = *(const short8*)swz128p(sST, n * 16 + fr, ks * 32 + kq * 8);
#pragma unroll
    for (int m = 0; m < 2; ++m)
#pragma unroll
      for (int n = 0; n < 4; ++n)
        acc2[m][n] = __builtin_amdgcn_mfma_f32_16x16x32_bf16(a[m], b[n], acc2[m][n], 0, 0, 0);
  }
  const float Dh = Dv[h];
  const short* cx = (const short*)convx;
#pragma unroll
  for (int m = 0; m < 2; ++m)
#pragma unroll
    for (int jj = 0; jj < 4; ++jj) {
      int i = wi + m * 16 + kq * 4 + jj;
      int t = t0 + i;
      float e2 = exp2f(scum2[i]);
      float vs[4];
      float ss = 0.f;
#pragma unroll
      for (int n = 0; n < 4; ++n) {
        int p = n * 16 + fr;
        float xv = bf2f(cx[(size_t)t * D_XB + g * 64 + p]);
        float zv = bf2f(((const short*)z)[(size_t)t * D_INNER + h * 64 + p]);
        float y = acc1[m][n][jj] + e2 * acc2[m][n][jj] + xv * Dh;
        float sz = zv / (1.f + expf(-zv));
        float v = y * sz;
        vs[n] = v;
        ss += v * v;
      }
      ss += __shfl_xor(ss, 1);
      ss += __shfl_xor(ss, 2);
      ss += __shfl_xor(ss, 4);
      ss += __shfl_xor(ss, 8);
      float rinv = rsqrtf(ss * (1.f / 64.f) + EPS);
#pragma unroll
      for (int n = 0; n < 4; ++n) {
        int p = n * 16 + fr;
        ((short*)normed)[(size_t)t * D_INNER + h * 64 + p] = f2bf(vs[n] * rinv * nw[h * 64 + p]);
      }
    }
}

// ---------------- launch ----------------
extern "C" void kernel_launch(void* const* d_in, const int* in_sizes, int n_in,
                              void* d_out, int out_size, void* d_ws, size_t ws_size,
                              hipStream_t stream) {
  const float* u       = (const float*)d_in[0];
  const float* W_in    = (const float*)d_in[1];
  const float* conv_w  = (const float*)d_in[2];
  const float* conv_b  = (const float*)d_in[3];
  const float* dt_bias = (const float*)d_in[4];
  const float* A_log   = (const float*)d_in[5];
  const float* Dv      = (const float*)d_in[6];
  const float* norm_w  = (const float*)d_in[7];
  const float* W_out   = (const float*)d_in[8];
  float* out = (float*)d_out;

  if (ws_size < WS_BYTES) {
    size_t n = (size_t)out_size;
    fill_kernel<<<(n + 255) / 256, 256, 0, stream>>>(out, n, 1000.0f);
    return;
  }

  char* wsb   = (char*)d_ws;
  bf16*  z    = (bf16*)(wsb);
  bf16*  raw  = (bf16*)(wsb + Z_BYTES);
  float* dtp  = (float*)(wsb + Z_BYTES + RAW_BYTES);
  float* cdec = (float*)(wsb + Z_BYTES + RAW_BYTES + DTP_BYTES);
  char*  R    = wsb + Z_BYTES + RAW_BYTES + DTP_BYTES + CDEC_BYTES;
  short* u_bf  = (short*)(R);
  short* WinT  = (short*)(R + U_BYTES);
  bf16*  convx = (bf16*)(R);                   // R .. +8.4MB (dead after passC)
  bf16*  normed = (bf16*)(R + U_BYTES);        // R+16.7MB .. +50.3MB (no alias w/ raw)
  short* Sbuf  = (short*)(R + CONV_BYTES);
  short* WoutT = (short*)(R);                  // R .. +16.7MB (after passC)

  // 0) casts for GEMM1
  cast_f32_bf16<<<(U_BYTES / 8 + 255) / 256, 256, 0, stream>>>(u, u_bf, U_BYTES / 8);
  {
    dim3 grid(NPAD / 32, D_MODEL / 128);
    transpose_cast<<<grid, 256, 0, stream>>>(W_in, WinT, D_MODEL, D_IN_PROJ);
  }
  // 1) GEMM1 (256x256, 4-phase/K-tile)
  gemm1_8ph<<<(NPAD / 256) * (SEQLEN / 256), 512, 0, stream>>>(u_bf, WinT, z, raw, dtp);
  // 2) conv + silu, x channels only (B/C conv fused into passA/passC)
  conv_silu_x<<<(SEQLEN * (D_XB / 8) + 255) / 256, 256, 0, stream>>>(raw, conv_w, conv_b, convx);
  // 3) dt softplus
  dt_softplus_kernel<<<(SEQLEN * NHEADS + 255) / 256, 256, 0, stream>>>(dtp, dt_bias);
  // 4) SSD pass A (MFMA, fused conv-B)
  {
    dim3 grid(NCHUNK, NHEADS);
    ssd_passA<<<grid, 256, 0, stream>>>(raw, convx, conv_w, conv_b, dtp, A_log, Sbuf, cdec);
  }
  // 5) SSD pass B
  {
    dim3 grid(NHEADS, 4);
    ssd_passB<<<grid, 256, 0, stream>>>(Sbuf, cdec);
  }
  // 6) SSD pass C (MFMA, fused conv-B/C) -> normed (non-aliasing)
  {
    dim3 grid(NCHUNK, NHEADS);
    ssd_passC<<<grid, 256, 0, stream>>>(z, raw, convx, conv_w, conv_b, dtp, A_log, Dv, norm_w, Sbuf, normed);
  }
  // 7) W_out transpose + GEMM2 (128x128, 2 blocks/CU)
  {
    dim3 grid(D_MODEL / 32, D_INNER / 128);
    transpose_cast<<<grid, 256, 0, stream>>>(W_out, WoutT, D_INNER, D_MODEL);
  }
  gemm2_8ph<<<(SEQLEN / 128) * (D_MODEL / 128), 256, 0, stream>>>((const short*)normed, WoutT, out);
}

// Round 17
// 544.682 us; speedup vs baseline: 1.1009x; 1.0851x over previous
//
#include <hip/hip_runtime.h>
#include <hip/hip_bf16.h>
#include <math.h>

typedef __hip_bfloat16 bf16;
typedef __attribute__((ext_vector_type(8))) short short8;
typedef __attribute__((ext_vector_type(4))) float f32x4;

#define D_MODEL   2048
#define D_INNER   4096
#define NHEADS    64
#define DSTATE    64
#define D_XB      1024
#define XB_HEADS  16
#define REP       4
#define DCONV     4
#define CHUNK     128
#define SEQLEN    4096
#define NCHUNK    (SEQLEN / CHUNK)                 // 32
#define D_IN_PROJ (2*D_INNER + 2*D_XB + NHEADS)    // 10304
#define NPAD      10496                            // 41*256
#define CONV_DIM  (D_INNER + 2*D_XB)               // 6144
#define EPS       1e-5f
#define LOG2E     1.44269504f

// ---------------- workspace layout (bytes) ----------------
#define Z_BYTES    ((size_t)SEQLEN * D_INNER * 2)                   // 33,554,432
#define RAW_BYTES  ((size_t)SEQLEN * CONV_DIM * 2)                  // 50,331,648
#define DTP_BYTES  ((size_t)SEQLEN * NHEADS * 4)                    //  1,048,576
#define CDEC_BYTES ((size_t)NCHUNK * NHEADS * 4)                    //      8,192
#define CONV_BYTES ((size_t)SEQLEN * CONV_DIM * 2)                  // 50,331,648
#define S_BYTES    ((size_t)NCHUNK * NHEADS * DSTATE * DSTATE * 4)
#define U_BYTES    ((size_t)SEQLEN * D_MODEL * 2)                   // 16,777,216
#define RREG_BYTES (CONV_BYTES + S_BYTES)                           // 83,886,080 (>= U+WinT)
#define WS_BYTES   (Z_BYTES + RAW_BYTES + DTP_BYTES + CDEC_BYTES + RREG_BYTES)

__device__ __forceinline__ short f2bf(float f) {
  bf16 h = __float2bfloat16(f);
  return *reinterpret_cast<short*>(&h);
}
__device__ __forceinline__ float bf2f(short s) {
  unsigned int u = ((unsigned int)(unsigned short)s) << 16;
  union { unsigned int u; float f; } c; c.u = u; return c.f;
}

__device__ __forceinline__ void gload_lds16(const void* g, void* l) {
  typedef __attribute__((address_space(1))) const unsigned int guint;
  typedef __attribute__((address_space(3))) unsigned int luint;
  __builtin_amdgcn_global_load_lds((guint*)g, (luint*)l, 16, 0, 0);
}

// swizzled LDS addressing helpers (involutions)
__device__ __forceinline__ char* swz128p(char* b, int r, int c) {
  int o = r * 128 + c * 2; o ^= (r & 7) << 4; return b + o;
}
__device__ __forceinline__ const char* swz128p(const char* b, int r, int c) {
  int o = r * 128 + c * 2; o ^= (r & 7) << 4; return b + o;
}
__device__ __forceinline__ char* swz256p(char* b, int r, int c) {
  int o = r * 256 + c * 2; o ^= (r & 15) << 4; return b + o;
}
__device__ __forceinline__ const char* swz256p(const char* b, int r, int c) {
  int o = r * 256 + c * 2; o ^= (r & 15) << 4; return b + o;
}

// ---------------- diagnostic fill ----------------
__global__ void fill_kernel(float* p, size_t n, float v) {
  size_t i = (size_t)blockIdx.x * blockDim.x + threadIdx.x;
  if (i < n) p[i] = v;
}

// ---------------- cast f32 -> bf16 ----------------
__global__ __launch_bounds__(256) void cast_f32_bf16(
    const float* __restrict__ in, short* __restrict__ out, size_t n4) {
  size_t i = (size_t)blockIdx.x * 256 + threadIdx.x;
  if (i >= n4) return;
  float4 v = ((const float4*)in)[i];
  short4 o;
  o.x = f2bf(v.x); o.y = f2bf(v.y); o.z = f2bf(v.z); o.w = f2bf(v.w);
  ((short4*)out)[i] = o;
}

// ---------------- transpose + cast v2: in[R][C] f32 -> out[Cpad][R] bf16 ----------
__global__ __launch_bounds__(256) void transpose_cast(
    const float* __restrict__ in, short* __restrict__ out, int R, int C) {
  __shared__ float tile[32][130];
  const int r0 = blockIdx.y * 128;
  const int c0 = blockIdx.x * 32;
  const int tid = threadIdx.x;
  {
    int cq = tid & 7;
    int rbase = tid >> 3;
    bool valid = (c0 + cq * 4) < C;
#pragma unroll
    for (int i = 0; i < 4; ++i) {
      int r = rbase + i * 32;
      float4 v = make_float4(0.f, 0.f, 0.f, 0.f);
      if (valid) v = *(const float4*)(in + (size_t)(r0 + r) * C + c0 + cq * 4);
      tile[cq * 4 + 0][r] = v.x;
      tile[cq * 4 + 1][r] = v.y;
      tile[cq * 4 + 2][r] = v.z;
      tile[cq * 4 + 3][r] = v.w;
    }
  }
  __syncthreads();
  {
    int rq = tid & 31;
    int cbase = tid >> 5;
#pragma unroll
    for (int i = 0; i < 4; ++i) {
      int c = cbase + i * 8;
      short4 o;
      o.x = f2bf(tile[c][rq * 4 + 0]);
      o.y = f2bf(tile[c][rq * 4 + 1]);
      o.z = f2bf(tile[c][rq * 4 + 2]);
      o.w = f2bf(tile[c][rq * 4 + 3]);
      *(short4*)(out + (size_t)(c0 + c) * R + r0 + rq * 4) = o;
    }
  }
}

// ================== BM x 256 phase-split GEMM core (round-7 schedule) =============
// A [M][K] bf16 row-major; Bt [N][K] bf16 row-major. 512 threads = 8 waves.
// One half staged per phase; counted vmcnt(NLA+2).

template<int NLOADS>
__device__ __forceinline__ void stage_half(const char* gtile, int rowbytes,
                                           char* ldst, int tid) {
#pragma unroll
  for (int i = 0; i < NLOADS; ++i) {
    int cid = i * 512 + tid;
    int r = cid >> 2;
    int pos = ((cid & 3) * 16) ^ (((r >> 1) & 3) << 4);
    gload_lds16(gtile + (size_t)r * rowbytes + pos, ldst + cid * 16);
  }
}

template<int BM>
__device__ __forceinline__ void compute_phase(const char* ldsA, const char* ldsB,
    int wm, int wn, int mh, int fr, int kqb, f32x4 (&acc)[BM / 32][4]) {
  constexpr int MF = BM / 64;
  short8 a[MF], b[4];
#pragma unroll
  for (int m = 0; m < MF; ++m) {
    int r = wm * (BM / 2) + mh * (BM / 4) + m * 16 + fr;
    a[m] = *(const short8*)(ldsA + r * 64 + (kqb ^ (((r >> 1) & 3) << 4)));
  }
#pragma unroll
  for (int n = 0; n < 4; ++n) {
    int r = wn * 64 + n * 16 + fr;
    b[n] = *(const short8*)(ldsB + r * 64 + (kqb ^ (((r >> 1) & 3) << 4)));
  }
  __builtin_amdgcn_s_setprio(1);
#pragma unroll
  for (int m = 0; m < MF; ++m)
#pragma unroll
    for (int n = 0; n < 4; ++n)
      acc[mh * MF + m][n] = __builtin_amdgcn_mfma_f32_16x16x32_bf16(a[m], b[n], acc[mh * MF + m][n], 0, 0, 0);
  __builtin_amdgcn_s_setprio(0);
}

template<int N>
__device__ __forceinline__ void wait_bar() {
  if constexpr (N == 0) asm volatile("s_waitcnt vmcnt(0)" ::: "memory");
  else if constexpr (N == 3) asm volatile("s_waitcnt vmcnt(3)" ::: "memory");
  else if constexpr (N == 4) asm volatile("s_waitcnt vmcnt(4)" ::: "memory");
  __builtin_amdgcn_s_barrier();
  __builtin_amdgcn_sched_barrier(0);
}

template<int BM>
__device__ __forceinline__ void gemm_core(const short* A, const short* Bt, int K,
    int rowBase, int colBase, char* lds, f32x4 (&acc)[BM / 32][4]) {
  constexpr int SA = BM * 64;            // A k-half bytes (16KB / 8KB)
  constexpr int NLA = SA / 8192;         // A loads/thread per half (2 / 1)
  constexpr int W = NLA + 2;             // steady-state vmcnt (4 / 3)
  const int tid = threadIdx.x, lane = tid & 63;
  const int w = tid >> 6, wm = w >> 2, wn = w & 3;
  const int fr = lane & 15, kqb = (lane >> 4) * 16;
  const int NT = K >> 6;
  const int rb = K * 2;
  char* ldsA = lds;
  char* ldsB = lds + 4 * SA;
  const char* Ag = (const char*)(A + (size_t)rowBase * K);
  const char* Bg = (const char*)(Bt + (size_t)colBase * K);
  stage_half<NLA>(Ag, rb, ldsA, tid);
  stage_half<2>(Bg, rb, ldsB, tid);
  stage_half<NLA>(Ag + 64, rb, ldsA + SA, tid);
  stage_half<2>(Bg + 64, rb, ldsB + 16384, tid);
  wait_bar<W>();
  for (int t = 0; t < NT; ++t) {
    const int cbA = (t & 1) * 2 * SA, nbA = ((t + 1) & 1) * 2 * SA;
    const int cbB = (t & 1) * 32768, nbB = ((t + 1) & 1) * 32768;
    const size_t ko = (size_t)(t + 1) * 128;
    const bool more = (t + 1 < NT);
    if (more) stage_half<NLA>(Ag + ko, rb, ldsA + nbA, tid);
    compute_phase<BM>(ldsA + cbA, ldsB + cbB, wm, wn, 0, fr, kqb, acc);
    if (more) stage_half<2>(Bg + ko, rb, ldsB + nbB, tid);
    compute_phase<BM>(ldsA + cbA, ldsB + cbB, wm, wn, 1, fr, kqb, acc);
    if (more) { wait_bar<W>(); } else { wait_bar<0>(); }
    if (more) stage_half<NLA>(Ag + ko + 64, rb, ldsA + nbA + SA, tid);
    compute_phase<BM>(ldsA + cbA + SA, ldsB + cbB + 16384, wm, wn, 0, fr, kqb, acc);
    if (more) stage_half<2>(Bg + ko + 64, rb, ldsB + nbB + 16384, tid);
    compute_phase<BM>(ldsA + cbA + SA, ldsB + cbB + 16384, wm, wn, 1, fr, kqb, acc);
    if (more) { wait_bar<W>(); } else { wait_bar<0>(); }
  }
}

// ---------------- GEMM1: zxbcdt = u @ W_in, split epilogue (raw dt write) --------
__global__ __launch_bounds__(512) void gemm1_8ph(
    const short* __restrict__ A, const short* __restrict__ Bt,
    bf16* __restrict__ z, bf16* __restrict__ raw, float* __restrict__ dtraw) {
  __shared__ __align__(16) char lds[131072];
  f32x4 acc[8][4] = {};
  const int bid = blockIdx.x;
  const int s = (bid & 7) * 82 + (bid >> 3);
  const int rowBase = (s & 15) * 256;
  const int colBase = (s >> 4) * 256;
  gemm_core<256>(A, Bt, D_MODEL, rowBase, colBase, lds, acc);
  const int lane = threadIdx.x & 63, w = threadIdx.x >> 6;
  const int wm = w >> 2, wn = w & 3;
  const int fr = lane & 15, kq = lane >> 4;
  const int r0 = rowBase + wm * 128 + kq * 4;
  const int c0 = colBase + wn * 64 + fr;
#pragma unroll
  for (int M = 0; M < 8; ++M)
#pragma unroll
    for (int n = 0; n < 4; ++n) {
      int col = c0 + n * 16;
#pragma unroll
      for (int j = 0; j < 4; ++j) {
        int row = r0 + M * 16 + j;
        float v = acc[M][n][j];
        if (col < D_INNER) {
          z[(size_t)row * D_INNER + col] = __float2bfloat16(v);
        } else if (col < D_INNER + CONV_DIM) {
          raw[(size_t)row * CONV_DIM + (col - D_INNER)] = __float2bfloat16(v);
        } else if (col < D_IN_PROJ) {
          dtraw[(size_t)row * NHEADS + (col - D_INNER - CONV_DIM)] = v;
        }
      }
    }
}

// ---------------- GEMM2: out = normed @ W_out (128x256, 256 blocks) --------------
__global__ __launch_bounds__(512) void gemm2_8ph(
    const short* __restrict__ A, const short* __restrict__ Bt,
    float* __restrict__ C) {
  __shared__ __align__(16) char lds[98304];
  f32x4 acc[4][4] = {};
  const int bid = blockIdx.x;
  const int s = (bid & 7) * 32 + (bid >> 3);
  const int rowBase = (s & 31) * 128;
  const int colBase = (s >> 5) * 256;
  gemm_core<128>(A, Bt, D_INNER, rowBase, colBase, lds, acc);
  const int lane = threadIdx.x & 63, w = threadIdx.x >> 6;
  const int wm = w >> 2, wn = w & 3;
  const int fr = lane & 15, kq = lane >> 4;
  const int r0 = rowBase + wm * 64 + kq * 4;
  const int c0 = colBase + wn * 64 + fr;
#pragma unroll
  for (int M = 0; M < 4; ++M)
#pragma unroll
    for (int n = 0; n < 4; ++n) {
      int col = c0 + n * 16;
#pragma unroll
      for (int j = 0; j < 4; ++j)
        C[(size_t)(r0 + M * 16 + j) * D_MODEL + col] = acc[M][n][j];
    }
}

// ---------------- conv1d + SiLU, vectorized (8 channels/thread) ----------------
__global__ __launch_bounds__(256) void conv_silu_kernel(
    const bf16* __restrict__ raw, const float* __restrict__ cw,
    const float* __restrict__ cb, bf16* __restrict__ convout) {
  int idx = blockIdx.x * 256 + threadIdx.x;
  if (idx >= SEQLEN * (CONV_DIM / 8)) return;
  int t = idx / (CONV_DIM / 8);
  int c8 = (idx % (CONV_DIM / 8)) * 8;
  float acc[8];
  float4 w[8];
#pragma unroll
  for (int q = 0; q < 8; ++q) {
    acc[q] = cb[c8 + q];
    w[q] = ((const float4*)cw)[c8 + q];
  }
#pragma unroll
  for (int k = 0; k < DCONV; ++k) {
    int tt = t - (DCONV - 1) + k;
    if (tt < 0) continue;
    short8 v = *(const short8*)((const short*)raw + (size_t)tt * CONV_DIM + c8);
#pragma unroll
    for (int q = 0; q < 8; ++q)
      acc[q] += bf2f(v[q]) * ((const float*)&w[q])[k];
  }
  short8 o;
#pragma unroll
  for (int q = 0; q < 8; ++q) {
    float s = acc[q] / (1.f + expf(-acc[q]));
    o[q] = f2bf(s);
  }
  *(short8*)((short*)convout + (size_t)t * CONV_DIM + c8) = o;
}

// ---------------- SSD pass A (MFMA, fused dt-softplus) ----------------
__global__ __launch_bounds__(256) void ssd_passA(
    const bf16* __restrict__ conv, const float* __restrict__ dtraw,
    const float* __restrict__ dt_bias, const float* __restrict__ A_log,
    short* __restrict__ Sbuf, float* __restrict__ cdec) {
  __shared__ __align__(16) char sBn[16384];
  __shared__ __align__(16) char sXn[16384];
  __shared__ __align__(16) char sBT[16384];
  __shared__ __align__(16) char sXT[16384];
  __shared__ float sdt[CHUNK], scum2[CHUNK], sw[CHUNK];
  const int chunk = blockIdx.x, h = blockIdx.y, g = h >> 2;
  const int tid = threadIdx.x, lane = tid & 63, wid = tid >> 6;
  const int t0 = chunk * CHUNK;
  const int fr = lane & 15, kq = lane >> 4;
  {
    const short* cg = (const short*)conv;
#pragma unroll
    for (int it = 0; it < 4; ++it) {
      int cid = tid + it * 256;
      int r = cid >> 3, c8 = (cid & 7) * 8;
      size_t rowoff = (size_t)(t0 + r) * CONV_DIM;
      *(short8*)swz128p(sBn, r, c8) = *(const short8*)(cg + rowoff + D_XB + g * 64 + c8);
      *(short8*)swz128p(sXn, r, c8) = *(const short8*)(cg + rowoff + g * 64 + c8);
    }
    if (tid < CHUNK) {
      float x = dtraw[(size_t)(t0 + tid) * NHEADS + h] + dt_bias[h];
      sdt[tid] = (x > 20.f) ? x : log1pf(expf(x));
    }
  }
  __syncthreads();
  if (tid < CHUNK) {
    float Ah2 = -expf(A_log[h]) * LOG2E;
    float s_all = 0.f, s_le = 0.f;
    for (int i = 0; i < CHUNK; ++i) {
      float v = sdt[i] * Ah2;
      s_all += v;
      if (i <= tid) s_le += v;
    }
    scum2[tid] = s_le;
    sw[tid] = exp2f(s_all - s_le) * sdt[tid];
    if (tid == 0) cdec[chunk * NHEADS + h] = exp2f(s_all);
  }
  __syncthreads();
  {
    const int col = tid & 63, jb = (tid >> 6) * 32;
#pragma unroll
    for (int it = 0; it < 32; ++it) {
      int j = jb + it;
      *(short*)swz256p(sBT, col, j) = *(const short*)swz128p(sBn, j, col);
      float xv = bf2f(*(const short*)swz128p(sXn, j, col));
      *(short*)swz256p(sXT, col, j) = f2bf(xv * sw[j]);
    }
  }
  __syncthreads();
  f32x4 acc[4] = {};
#pragma unroll
  for (int ks = 0; ks < 4; ++ks) {
    short8 a = *(const short8*)swz256p(sXT, wid * 16 + fr, ks * 32 + kq * 8);
    short8 b[4];
#pragma unroll
    for (int n = 0; n < 4; ++n) b[n] = *(const short8*)swz256p(sBT, n * 16 + fr, ks * 32 + kq * 8);
#pragma unroll
    for (int n = 0; n < 4; ++n)
      acc[n] = __builtin_amdgcn_mfma_f32_16x16x32_bf16(a, b[n], acc[n], 0, 0, 0);
  }
  short* So = Sbuf + ((size_t)(chunk * NHEADS + h)) * (DSTATE * DSTATE);
#pragma unroll
  for (int n = 0; n < 4; ++n)
#pragma unroll
    for (int jj = 0; jj < 4; ++jj) {
      int p = wid * 16 + kq * 4 + jj;
      int nc = n * 16 + fr;
      So[p * 64 + nc] = f2bf(acc[n][jj]);
    }
}

// ---------------- SSD pass B: recurrence, in-place S->Hprev (bf16) ----------------
__global__ __launch_bounds__(256) void ssd_passB(
    short* __restrict__ Sbuf, const float* __restrict__ cdec) {
  const int h = blockIdx.x;
  const int base = blockIdx.y * 1024 + threadIdx.x * 4;
  float H[4] = {};
  for (int c = 0; c < NCHUNK; ++c) {
    short4* Sc = (short4*)(Sbuf + ((size_t)(c * NHEADS + h)) * (DSTATE * DSTATE) + base);
    short4 v = *Sc;
    short4 o;
    o.x = f2bf(H[0]); o.y = f2bf(H[1]); o.z = f2bf(H[2]); o.w = f2bf(H[3]);
    *Sc = o;
    float dec = cdec[c * NHEADS + h];
    H[0] = dec * H[0] + bf2f(v.x);
    H[1] = dec * H[1] + bf2f(v.y);
    H[2] = dec * H[2] + bf2f(v.z);
    H[3] = dec * H[3] + bf2f(v.w);
  }
}

// ---------------- SSD pass C (MFMA, fused dt-softplus) ----------------
__global__ __launch_bounds__(256) void ssd_passC(
    const bf16* __restrict__ z, const bf16* __restrict__ conv,
    const float* __restrict__ dtraw, const float* __restrict__ dt_bias,
    const float* __restrict__ A_log, const float* __restrict__ Dv,
    const float* __restrict__ nw, const short* __restrict__ Hprev,
    bf16* __restrict__ normed) {
  __shared__ __align__(16) char sC[16384];
  __shared__ __align__(16) char sBX[16384];
  __shared__ __align__(16) char sP[32768];
  __shared__ __align__(16) char sST[8192];
  __shared__ float sdt[CHUNK], scum2[CHUNK];
  const int chunk = blockIdx.x, h = blockIdx.y, g = h >> 2;
  const int tid = threadIdx.x, lane = tid & 63, wid = tid >> 6;
  const int t0 = chunk * CHUNK;
  const int fr = lane & 15, kq = lane >> 4;
  const int wi = wid * 32;
  {
    const short* cg = (const short*)conv;
#pragma unroll
    for (int it = 0; it < 4; ++it) {
      int cid = tid + it * 256;
      int r = cid >> 3, c8 = (cid & 7) * 8;
      size_t rowoff = (size_t)(t0 + r) * CONV_DIM;
      *(short8*)swz128p(sC, r, c8) = *(const short8*)(cg + rowoff + 2 * D_XB + h * 64 + c8);
      *(short8*)swz128p(sBX, r, c8) = *(const short8*)(cg + rowoff + D_XB + g * 64 + c8);
      *(short8*)swz128p(sP + 16384, r, c8) = *(const short8*)(cg + rowoff + g * 64 + c8);
    }
    if (tid < CHUNK) {
      float x = dtraw[(size_t)(t0 + tid) * NHEADS + h] + dt_bias[h];
      sdt[tid] = (x > 20.f) ? x : log1pf(expf(x));
    }
  }
  __syncthreads();
  if (tid < CHUNK) {
    float Ah2 = -expf(A_log[h]) * LOG2E;
    float s_le = 0.f;
    for (int i = 0; i <= tid; ++i) s_le += sdt[i] * Ah2;
    scum2[tid] = s_le;
  }
  __syncthreads();
  f32x4 accG[2][8] = {};
#pragma unroll
  for (int ks = 0; ks < 2; ++ks) {
    short8 a[2], b[8];
#pragma unroll
    for (int m = 0; m < 2; ++m)
      a[m] = *(const short8*)swz128p(sC, wi + m * 16 + fr, ks * 32 + kq * 8);
#pragma unroll
    for (int n = 0; n < 8; ++n)
      b[n] = *(const short8*)swz128p(sBX, n * 16 + fr, ks * 32 + kq * 8);
#pragma unroll
    for (int m = 0; m < 2; ++m)
#pragma unroll
      for (int n = 0; n < 8; ++n)
        accG[m][n] = __builtin_amdgcn_mfma_f32_16x16x32_bf16(a[m], b[n], accG[m][n], 0, 0, 0);
  }
  __syncthreads();
  {
    const int p = tid & 63, jb = (tid >> 6) * 32;
#pragma unroll
    for (int it = 0; it < 32; ++it) {
      int j = jb + it;
      *(short*)swz256p(sBX, p, j) = *(const short*)swz128p(sP + 16384, j, p);
    }
    const short* Hp = Hprev + ((size_t)(chunk * NHEADS + h)) * (DSTATE * DSTATE);
#pragma unroll
    for (int it = 0; it < 2; ++it) {
      int cid = tid + it * 256;
      int pr = cid >> 3, c8 = (cid & 7) * 8;
      *(short8*)swz128p(sST, pr, c8) = *(const short8*)(Hp + pr * 64 + c8);
    }
  }
  __syncthreads();
#pragma unroll
  for (int m = 0; m < 2; ++m)
#pragma unroll
    for (int jj = 0; jj < 4; ++jj) {
      int i = wi + m * 16 + kq * 4 + jj;
      float ci = scum2[i];
#pragma unroll
      for (int n = 0; n < 8; ++n) {
        int j = n * 16 + fr;
        float w = (j <= i) ? exp2f(ci - scum2[j]) * sdt[j] : 0.f;
        *(short*)swz256p(sP, i, j) = f2bf(accG[m][n][jj] * w);
      }
    }
  __syncthreads();
  f32x4 acc1[2][4] = {};
#pragma unroll
  for (int ks = 0; ks < 4; ++ks) {
    short8 a[2], b[4];
#pragma unroll
    for (int m = 0; m < 2; ++m)
      a[m] = *(const short8*)swz256p(sP, wi + m * 16 + fr, ks * 32 + kq * 8);
#pragma unroll
    for (int n = 0; n < 4; ++n)
      b[n] = *(const short8*)swz256p(sBX, n * 16 + fr, ks * 32 + kq * 8);
#pragma unroll
    for (int m = 0; m < 2; ++m)
#pragma unroll
      for (int n = 0; n < 4; ++n)
        acc1[m][n] = __builtin_amdgcn_mfma_f32_16x16x32_bf16(a[m], b[n], acc1[m][n], 0, 0, 0);
  }
  f32x4 acc2[2][4] = {};
#pragma unroll
  for (int ks = 0; ks < 2; ++ks) {
    short8 a[2], b[4];
#pragma unroll
    for (int m = 0; m < 2; ++m)
      a[m] = *(const short8*)swz128p(sC, wi + m * 16 + fr, ks * 32 + kq * 8);
#pragma unroll
    for (int n = 0; n < 4; ++n)
      b[n] = *(const short8*)swz128p(sST, n * 16 + fr, ks * 32 + kq * 8);
#pragma unroll
    for (int m = 0; m < 2; ++m)
#pragma unroll
      for (int n = 0; n < 4; ++n)
        acc2[m][n] = __builtin_amdgcn_mfma_f32_16x16x32_bf16(a[m], b[n], acc2[m][n], 0, 0, 0);
  }
  const float Dh = Dv[h];
#pragma unroll
  for (int m = 0; m < 2; ++m)
#pragma unroll
    for (int jj = 0; jj < 4; ++jj) {
      int i = wi + m * 16 + kq * 4 + jj;
      int t = t0 + i;
      float e2 = exp2f(scum2[i]);
      float vs[4];
      float ss = 0.f;
#pragma unroll
      for (int n = 0; n < 4; ++n) {
        int p = n * 16 + fr;
        float xv = bf2f(((const short*)conv)[(size_t)t * CONV_DIM + g * 64 + p]);
        float zv = bf2f(((const short*)z)[(size_t)t * D_INNER + h * 64 + p]);
        float y = acc1[m][n][jj] + e2 * acc2[m][n][jj] + xv * Dh;
        float sz = zv / (1.f + expf(-zv));
        float v = y * sz;
        vs[n] = v;
        ss += v * v;
      }
      ss += __shfl_xor(ss, 1);
      ss += __shfl_xor(ss, 2);
      ss += __shfl_xor(ss, 4);
      ss += __shfl_xor(ss, 8);
      float rinv = rsqrtf(ss * (1.f / 64.f) + EPS);
#pragma unroll
      for (int n = 0; n < 4; ++n) {
        int p = n * 16 + fr;
        ((short*)normed)[(size_t)t * D_INNER + h * 64 + p] = f2bf(vs[n] * rinv * nw[h * 64 + p]);
      }
    }
}

// ---------------- launch ----------------
extern "C" void kernel_launch(void* const* d_in, const int* in_sizes, int n_in,
                              void* d_out, int out_size, void* d_ws, size_t ws_size,
                              hipStream_t stream) {
  const float* u       = (const float*)d_in[0];
  const float* W_in    = (const float*)d_in[1];
  const float* conv_w  = (const float*)d_in[2];
  const float* conv_b  = (const float*)d_in[3];
  const float* dt_bias = (const float*)d_in[4];
  const float* A_log   = (const float*)d_in[5];
  const float* Dv      = (const float*)d_in[6];
  const float* norm_w  = (const float*)d_in[7];
  const float* W_out   = (const float*)d_in[8];
  float* out = (float*)d_out;

  if (ws_size < WS_BYTES) {
    size_t n = (size_t)out_size;
    fill_kernel<<<(n + 255) / 256, 256, 0, stream>>>(out, n, 1000.0f);
    return;
  }

  char* wsb   = (char*)d_ws;
  bf16*  z    = (bf16*)(wsb);
  bf16*  raw  = (bf16*)(wsb + Z_BYTES);
  float* dtp  = (float*)(wsb + Z_BYTES + RAW_BYTES);
  float* cdec = (float*)(wsb + Z_BYTES + RAW_BYTES + DTP_BYTES);
  char*  R    = wsb + Z_BYTES + RAW_BYTES + DTP_BYTES + CDEC_BYTES;
  short* u_bf  = (short*)(R);
  short* WinT  = (short*)(R + U_BYTES);
  bf16*  conv  = (bf16*)(R);
  short* Sbuf  = (short*)(R + CONV_BYTES);
  short* WoutT = (short*)(R);
  bf16*  normed = raw;   // raw dead after conv; passC reads conv buffer only

  // 0) casts for GEMM1
  cast_f32_bf16<<<(U_BYTES / 8 + 255) / 256, 256, 0, stream>>>(u, u_bf, U_BYTES / 8);
  {
    dim3 grid(NPAD / 32, D_MODEL / 128);
    transpose_cast<<<grid, 256, 0, stream>>>(W_in, WinT, D_MODEL, D_IN_PROJ);
  }
  // 1) GEMM1 (256x256, round-7 schedule)
  gemm1_8ph<<<(NPAD / 256) * (SEQLEN / 256), 512, 0, stream>>>(u_bf, WinT, z, raw, dtp);
  // 2) conv + silu (vectorized, all channels)
  conv_silu_kernel<<<(SEQLEN * (CONV_DIM / 8) + 255) / 256, 256, 0, stream>>>(raw, conv_w, conv_b, conv);
  // 3) SSD pass A (MFMA, fused dt-softplus)
  {
    dim3 grid(NCHUNK, NHEADS);
    ssd_passA<<<grid, 256, 0, stream>>>(conv, dtp, dt_bias, A_log, Sbuf, cdec);
  }
  // 4) SSD pass B
  {
    dim3 grid(NHEADS, 4);
    ssd_passB<<<grid, 256, 0, stream>>>(Sbuf, cdec);
  }
  // 5) SSD pass C (MFMA, fused dt-softplus) -> normed (aliases raw)
  {
    dim3 grid(NCHUNK, NHEADS);
    ssd_passC<<<grid, 256, 0, stream>>>(z, conv, dtp, dt_bias, A_log, Dv, norm_w, Sbuf, normed);
  }
  // 6) W_out transpose + GEMM2 (128x256)
  {
    dim3 grid(D_MODEL / 32, D_INNER / 128);
    transpose_cast<<<grid, 256, 0, stream>>>(W_out, WoutT, D_INNER, D_MODEL);
  }
  gemm2_8ph<<<(SEQLEN / 128) * (D_MODEL / 256), 512, 0, stream>>>((const short*)normed, WoutT, out);
}

// Round 18
// 534.950 us; speedup vs baseline: 1.1210x; 1.0182x over previous
//
#include <hip/hip_runtime.h>
#include <hip/hip_bf16.h>
#include <math.h>

typedef __hip_bfloat16 bf16;
typedef __attribute__((ext_vector_type(8))) short short8;
typedef __attribute__((ext_vector_type(4))) float f32x4;

#define D_MODEL   2048
#define D_INNER   4096
#define NHEADS    64
#define DSTATE    64
#define D_XB      1024
#define XB_HEADS  16
#define REP       4
#define DCONV     4
#define CHUNK     128
#define SEQLEN    4096
#define NCHUNK    (SEQLEN / CHUNK)                 // 32
#define D_IN_PROJ (2*D_INNER + 2*D_XB + NHEADS)    // 10304
#define NPAD      10496                            // 41*256
#define CONV_DIM  (D_INNER + 2*D_XB)               // 6144
#define EPS       1e-5f
#define LOG2E     1.44269504f

// ---------------- workspace layout (bytes) ----------------
#define Z_BYTES    ((size_t)SEQLEN * D_INNER * 2)                   // 33,554,432
#define RAW_BYTES  ((size_t)SEQLEN * CONV_DIM * 2)                  // 50,331,648
#define DTP_BYTES  ((size_t)SEQLEN * NHEADS * 4)                    //  1,048,576
#define CDEC_BYTES ((size_t)NCHUNK * NHEADS * 4)                    //      8,192
#define CONV_BYTES ((size_t)SEQLEN * CONV_DIM * 2)                  // 50,331,648
#define S_BYTES    ((size_t)NCHUNK * NHEADS * DSTATE * DSTATE * 4)
#define U_BYTES    ((size_t)SEQLEN * D_MODEL * 2)                   // 16,777,216
#define RREG_BYTES (CONV_BYTES + S_BYTES)                           // 83,886,080 (>= U+WinT)
#define WS_BYTES   (Z_BYTES + RAW_BYTES + DTP_BYTES + CDEC_BYTES + RREG_BYTES)

__device__ __forceinline__ short f2bf(float f) {
  bf16 h = __float2bfloat16(f);
  return *reinterpret_cast<short*>(&h);
}
__device__ __forceinline__ float bf2f(short s) {
  unsigned int u = ((unsigned int)(unsigned short)s) << 16;
  union { unsigned int u; float f; } c; c.u = u; return c.f;
}

__device__ __forceinline__ void gload_lds16(const void* g, void* l) {
  typedef __attribute__((address_space(1))) const unsigned int guint;
  typedef __attribute__((address_space(3))) unsigned int luint;
  __builtin_amdgcn_global_load_lds((guint*)g, (luint*)l, 16, 0, 0);
}

// swizzled LDS addressing helpers (involutions)
__device__ __forceinline__ char* swz128p(char* b, int r, int c) {
  int o = r * 128 + c * 2; o ^= (r & 7) << 4; return b + o;
}
__device__ __forceinline__ const char* swz128p(const char* b, int r, int c) {
  int o = r * 128 + c * 2; o ^= (r & 7) << 4; return b + o;
}
__device__ __forceinline__ char* swz256p(char* b, int r, int c) {
  int o = r * 256 + c * 2; o ^= (r & 15) << 4; return b + o;
}
__device__ __forceinline__ const char* swz256p(const char* b, int r, int c) {
  int o = r * 256 + c * 2; o ^= (r & 15) << 4; return b + o;
}

// ---------------- diagnostic fill ----------------
__global__ void fill_kernel(float* p, size_t n, float v) {
  size_t i = (size_t)blockIdx.x * blockDim.x + threadIdx.x;
  if (i < n) p[i] = v;
}

// ---------------- cast f32 -> bf16 ----------------
__global__ __launch_bounds__(256) void cast_f32_bf16(
    const float* __restrict__ in, short* __restrict__ out, size_t n4) {
  size_t i = (size_t)blockIdx.x * 256 + threadIdx.x;
  if (i >= n4) return;
  float4 v = ((const float4*)in)[i];
  short4 o;
  o.x = f2bf(v.x); o.y = f2bf(v.y); o.z = f2bf(v.z); o.w = f2bf(v.w);
  ((short4*)out)[i] = o;
}

// ---------------- transpose + cast v2: in[R][C] f32 -> out[Cpad][R] bf16 ----------
__global__ __launch_bounds__(256) void transpose_cast(
    const float* __restrict__ in, short* __restrict__ out, int R, int C) {
  __shared__ float tile[32][130];
  const int r0 = blockIdx.y * 128;
  const int c0 = blockIdx.x * 32;
  const int tid = threadIdx.x;
  {
    int cq = tid & 7;
    int rbase = tid >> 3;
    bool valid = (c0 + cq * 4) < C;
#pragma unroll
    for (int i = 0; i < 4; ++i) {
      int r = rbase + i * 32;
      float4 v = make_float4(0.f, 0.f, 0.f, 0.f);
      if (valid) v = *(const float4*)(in + (size_t)(r0 + r) * C + c0 + cq * 4);
      tile[cq * 4 + 0][r] = v.x;
      tile[cq * 4 + 1][r] = v.y;
      tile[cq * 4 + 2][r] = v.z;
      tile[cq * 4 + 3][r] = v.w;
    }
  }
  __syncthreads();
  {
    int rq = tid & 31;
    int cbase = tid >> 5;
#pragma unroll
    for (int i = 0; i < 4; ++i) {
      int c = cbase + i * 8;
      short4 o;
      o.x = f2bf(tile[c][rq * 4 + 0]);
      o.y = f2bf(tile[c][rq * 4 + 1]);
      o.z = f2bf(tile[c][rq * 4 + 2]);
      o.w = f2bf(tile[c][rq * 4 + 3]);
      *(short4*)(out + (size_t)(c0 + c) * R + r0 + rq * 4) = o;
    }
  }
}

// ================== BM x 256 phase-split GEMM core (round-7 schedule) =============

template<int NLOADS>
__device__ __forceinline__ void stage_half(const char* gtile, int rowbytes,
                                           char* ldst, int tid) {
#pragma unroll
  for (int i = 0; i < NLOADS; ++i) {
    int cid = i * 512 + tid;
    int r = cid >> 2;
    int pos = ((cid & 3) * 16) ^ (((r >> 1) & 3) << 4);
    gload_lds16(gtile + (size_t)r * rowbytes + pos, ldst + cid * 16);
  }
}

template<int BM>
__device__ __forceinline__ void compute_phase(const char* ldsA, const char* ldsB,
    int wm, int wn, int mh, int fr, int kqb, f32x4 (&acc)[BM / 32][4]) {
  constexpr int MF = BM / 64;
  short8 a[MF], b[4];
#pragma unroll
  for (int m = 0; m < MF; ++m) {
    int r = wm * (BM / 2) + mh * (BM / 4) + m * 16 + fr;
    a[m] = *(const short8*)(ldsA + r * 64 + (kqb ^ (((r >> 1) & 3) << 4)));
  }
#pragma unroll
  for (int n = 0; n < 4; ++n) {
    int r = wn * 64 + n * 16 + fr;
    b[n] = *(const short8*)(ldsB + r * 64 + (kqb ^ (((r >> 1) & 3) << 4)));
  }
  __builtin_amdgcn_s_setprio(1);
#pragma unroll
  for (int m = 0; m < MF; ++m)
#pragma unroll
    for (int n = 0; n < 4; ++n)
      acc[mh * MF + m][n] = __builtin_amdgcn_mfma_f32_16x16x32_bf16(a[m], b[n], acc[mh * MF + m][n], 0, 0, 0);
  __builtin_amdgcn_s_setprio(0);
}

template<int N>
__device__ __forceinline__ void wait_bar() {
  if constexpr (N == 0) asm volatile("s_waitcnt vmcnt(0)" ::: "memory");
  else if constexpr (N == 3) asm volatile("s_waitcnt vmcnt(3)" ::: "memory");
  else if constexpr (N == 4) asm volatile("s_waitcnt vmcnt(4)" ::: "memory");
  __builtin_amdgcn_s_barrier();
  __builtin_amdgcn_sched_barrier(0);
}

template<int BM>
__device__ __forceinline__ void gemm_core(const short* A, const short* Bt, int K,
    int rowBase, int colBase, char* lds, f32x4 (&acc)[BM / 32][4]) {
  constexpr int SA = BM * 64;            // A k-half bytes (16KB / 8KB)
  constexpr int NLA = SA / 8192;         // A loads/thread per half (2 / 1)
  constexpr int W = NLA + 2;             // steady-state vmcnt (4 / 3)
  const int tid = threadIdx.x, lane = tid & 63;
  const int w = tid >> 6, wm = w >> 2, wn = w & 3;
  const int fr = lane & 15, kqb = (lane >> 4) * 16;
  const int NT = K >> 6;
  const int rb = K * 2;
  char* ldsA = lds;
  char* ldsB = lds + 4 * SA;
  const char* Ag = (const char*)(A + (size_t)rowBase * K);
  const char* Bg = (const char*)(Bt + (size_t)colBase * K);
  stage_half<NLA>(Ag, rb, ldsA, tid);
  stage_half<2>(Bg, rb, ldsB, tid);
  stage_half<NLA>(Ag + 64, rb, ldsA + SA, tid);
  stage_half<2>(Bg + 64, rb, ldsB + 16384, tid);
  wait_bar<W>();
  for (int t = 0; t < NT; ++t) {
    const int cbA = (t & 1) * 2 * SA, nbA = ((t + 1) & 1) * 2 * SA;
    const int cbB = (t & 1) * 32768, nbB = ((t + 1) & 1) * 32768;
    const size_t ko = (size_t)(t + 1) * 128;
    const bool more = (t + 1 < NT);
    if (more) stage_half<NLA>(Ag + ko, rb, ldsA + nbA, tid);
    compute_phase<BM>(ldsA + cbA, ldsB + cbB, wm, wn, 0, fr, kqb, acc);
    if (more) stage_half<2>(Bg + ko, rb, ldsB + nbB, tid);
    compute_phase<BM>(ldsA + cbA, ldsB + cbB, wm, wn, 1, fr, kqb, acc);
    if (more) { wait_bar<W>(); } else { wait_bar<0>(); }
    if (more) stage_half<NLA>(Ag + ko + 64, rb, ldsA + nbA + SA, tid);
    compute_phase<BM>(ldsA + cbA + SA, ldsB + cbB + 16384, wm, wn, 0, fr, kqb, acc);
    if (more) stage_half<2>(Bg + ko + 64, rb, ldsB + nbB + 16384, tid);
    compute_phase<BM>(ldsA + cbA + SA, ldsB + cbB + 16384, wm, wn, 1, fr, kqb, acc);
    if (more) { wait_bar<W>(); } else { wait_bar<0>(); }
  }
}

// ---------------- GEMM1: zxbcdt = u @ W_in, split epilogue (raw dt write) --------
__global__ __launch_bounds__(512) void gemm1_8ph(
    const short* __restrict__ A, const short* __restrict__ Bt,
    bf16* __restrict__ z, bf16* __restrict__ raw, float* __restrict__ dtraw) {
  __shared__ __align__(16) char lds[131072];
  f32x4 acc[8][4] = {};
  const int bid = blockIdx.x;
  const int s = (bid & 7) * 82 + (bid >> 3);
  const int rowBase = (s & 15) * 256;
  const int colBase = (s >> 4) * 256;
  gemm_core<256>(A, Bt, D_MODEL, rowBase, colBase, lds, acc);
  const int lane = threadIdx.x & 63, w = threadIdx.x >> 6;
  const int wm = w >> 2, wn = w & 3;
  const int fr = lane & 15, kq = lane >> 4;
  const int r0 = rowBase + wm * 128 + kq * 4;
  const int c0 = colBase + wn * 64 + fr;
#pragma unroll
  for (int M = 0; M < 8; ++M)
#pragma unroll
    for (int n = 0; n < 4; ++n) {
      int col = c0 + n * 16;
#pragma unroll
      for (int j = 0; j < 4; ++j) {
        int row = r0 + M * 16 + j;
        float v = acc[M][n][j];
        if (col < D_INNER) {
          z[(size_t)row * D_INNER + col] = __float2bfloat16(v);
        } else if (col < D_INNER + CONV_DIM) {
          raw[(size_t)row * CONV_DIM + (col - D_INNER)] = __float2bfloat16(v);
        } else if (col < D_IN_PROJ) {
          dtraw[(size_t)row * NHEADS + (col - D_INNER - CONV_DIM)] = v;
        }
      }
    }
}

// ---------------- GEMM2: out = normed @ W_out (128x256, 256 blocks) --------------
__global__ __launch_bounds__(512) void gemm2_8ph(
    const short* __restrict__ A, const short* __restrict__ Bt,
    float* __restrict__ C) {
  __shared__ __align__(16) char lds[98304];
  f32x4 acc[4][4] = {};
  const int bid = blockIdx.x;
  const int s = (bid & 7) * 32 + (bid >> 3);
  const int rowBase = (s & 31) * 128;
  const int colBase = (s >> 5) * 256;
  gemm_core<128>(A, Bt, D_INNER, rowBase, colBase, lds, acc);
  const int lane = threadIdx.x & 63, w = threadIdx.x >> 6;
  const int wm = w >> 2, wn = w & 3;
  const int fr = lane & 15, kq = lane >> 4;
  const int r0 = rowBase + wm * 64 + kq * 4;
  const int c0 = colBase + wn * 64 + fr;
#pragma unroll
  for (int M = 0; M < 4; ++M)
#pragma unroll
    for (int n = 0; n < 4; ++n) {
      int col = c0 + n * 16;
#pragma unroll
      for (int j = 0; j < 4; ++j)
        C[(size_t)(r0 + M * 16 + j) * D_MODEL + col] = acc[M][n][j];
    }
}

// ---------------- conv1d + SiLU, vectorized (8 channels/thread) ----------------
__global__ __launch_bounds__(256) void conv_silu_kernel(
    const bf16* __restrict__ raw, const float* __restrict__ cw,
    const float* __restrict__ cb, bf16* __restrict__ convout) {
  int idx = blockIdx.x * 256 + threadIdx.x;
  if (idx >= SEQLEN * (CONV_DIM / 8)) return;
  int t = idx / (CONV_DIM / 8);
  int c8 = (idx % (CONV_DIM / 8)) * 8;
  float acc[8];
  float4 w[8];
#pragma unroll
  for (int q = 0; q < 8; ++q) {
    acc[q] = cb[c8 + q];
    w[q] = ((const float4*)cw)[c8 + q];
  }
#pragma unroll
  for (int k = 0; k < DCONV; ++k) {
    int tt = t - (DCONV - 1) + k;
    if (tt < 0) continue;
    short8 v = *(const short8*)((const short*)raw + (size_t)tt * CONV_DIM + c8);
#pragma unroll
    for (int q = 0; q < 8; ++q)
      acc[q] += bf2f(v[q]) * ((const float*)&w[q])[k];
  }
  short8 o;
#pragma unroll
  for (int q = 0; q < 8; ++q) {
    float s = acc[q] / (1.f + expf(-acc[q]));
    o[q] = f2bf(s);
  }
  *(short8*)((short*)convout + (size_t)t * CONV_DIM + c8) = o;
}

// ---------------- SSD pass A (reg-staged, parallel scan, fused softplus) ---------
__global__ __launch_bounds__(256) void ssd_passA(
    const bf16* __restrict__ conv, const float* __restrict__ dtraw,
    const float* __restrict__ dt_bias, const float* __restrict__ A_log,
    short* __restrict__ Sbuf, float* __restrict__ cdec) {
  __shared__ __align__(16) char sBT[16384];
  __shared__ __align__(16) char sXT[16384];
  __shared__ float sdt[CHUNK], sw[CHUNK], stot[2];
  const int chunk = blockIdx.x, h = blockIdx.y, g = h >> 2;
  const int tid = threadIdx.x, lane = tid & 63, wid = tid >> 6;
  const int t0 = chunk * CHUNK;
  const int fr = lane & 15, kq = lane >> 4;
  // stage B, X into registers (coalesced row loads)
  short8 rB[4], rX[4];
  {
    const short* cg = (const short*)conv;
#pragma unroll
    for (int it = 0; it < 4; ++it) {
      int cid = tid + it * 256;
      int r = cid >> 3, c8 = (cid & 7) * 8;
      size_t rowoff = (size_t)(t0 + r) * CONV_DIM;
      rB[it] = *(const short8*)(cg + rowoff + D_XB + g * 64 + c8);
      rX[it] = *(const short8*)(cg + rowoff + g * 64 + c8);
    }
    if (tid < CHUNK) {
      float x = dtraw[(size_t)(t0 + tid) * NHEADS + h] + dt_bias[h];
      sdt[tid] = (x > 20.f) ? x : log1pf(expf(x));
    }
  }
  __syncthreads();
  // parallel inclusive scan of sdt*Ah2 over 128 (2 waves)
  const float Ah2 = -expf(A_log[h]) * LOG2E;
  float s_incl = 0.f;
  if (tid < CHUNK) {
    s_incl = sdt[tid] * Ah2;
#pragma unroll
    for (int off = 1; off < 64; off <<= 1) {
      float tt = __shfl_up(s_incl, off);
      if (lane >= off) s_incl += tt;
    }
    if (lane == 63) stot[wid] = s_incl;
  }
  __syncthreads();
  {
    float s_all = stot[0] + stot[1];
    if (tid < CHUNK) {
      float s = s_incl + ((tid >= 64) ? stot[0] : 0.f);
      sw[tid] = exp2f(s_all - s) * sdt[tid];
    }
    if (tid == 0) cdec[chunk * NHEADS + h] = exp2f(s_all);
  }
  __syncthreads();
  // direct transposed writes from registers: BT[n][j], XT[p][j] (*w_j)
#pragma unroll
  for (int it = 0; it < 4; ++it) {
    int cid = tid + it * 256;
    int r = cid >> 3, c8 = (cid & 7) * 8;
    float swr = sw[r];
#pragma unroll
    for (int q = 0; q < 8; ++q) {
      *(short*)swz256p(sBT, c8 + q, r) = rB[it][q];
      *(short*)swz256p(sXT, c8 + q, r) = f2bf(bf2f(rX[it][q]) * swr);
    }
  }
  __syncthreads();
  f32x4 acc[4] = {};
#pragma unroll
  for (int ks = 0; ks < 4; ++ks) {
    short8 a = *(const short8*)swz256p(sXT, wid * 16 + fr, ks * 32 + kq * 8);
    short8 b[4];
#pragma unroll
    for (int n = 0; n < 4; ++n) b[n] = *(const short8*)swz256p(sBT, n * 16 + fr, ks * 32 + kq * 8);
#pragma unroll
    for (int n = 0; n < 4; ++n)
      acc[n] = __builtin_amdgcn_mfma_f32_16x16x32_bf16(a, b[n], acc[n], 0, 0, 0);
  }
  short* So = Sbuf + ((size_t)(chunk * NHEADS + h)) * (DSTATE * DSTATE);
#pragma unroll
  for (int n = 0; n < 4; ++n)
#pragma unroll
    for (int jj = 0; jj < 4; ++jj) {
      int p = wid * 16 + kq * 4 + jj;
      int nc = n * 16 + fr;
      So[p * 64 + nc] = f2bf(acc[n][jj]);
    }
}

// ---------------- SSD pass B: recurrence, in-place S->Hprev (bf16) ----------------
__global__ __launch_bounds__(256) void ssd_passB(
    short* __restrict__ Sbuf, const float* __restrict__ cdec) {
  const int h = blockIdx.x;
  const int base = blockIdx.y * 1024 + threadIdx.x * 4;
  float H[4] = {};
  for (int c = 0; c < NCHUNK; ++c) {
    short4* Sc = (short4*)(Sbuf + ((size_t)(c * NHEADS + h)) * (DSTATE * DSTATE) + base);
    short4 v = *Sc;
    short4 o;
    o.x = f2bf(H[0]); o.y = f2bf(H[1]); o.z = f2bf(H[2]); o.w = f2bf(H[3]);
    *Sc = o;
    float dec = cdec[c * NHEADS + h];
    H[0] = dec * H[0] + bf2f(v.x);
    H[1] = dec * H[1] + bf2f(v.y);
    H[2] = dec * H[2] + bf2f(v.z);
    H[3] = dec * H[3] + bf2f(v.w);
  }
}

// ---------------- SSD pass C (MFMA, reg-X, parallel scan, fused softplus) --------
__global__ __launch_bounds__(256) void ssd_passC(
    const bf16* __restrict__ z, const bf16* __restrict__ conv,
    const float* __restrict__ dtraw, const float* __restrict__ dt_bias,
    const float* __restrict__ A_log, const float* __restrict__ Dv,
    const float* __restrict__ nw, const short* __restrict__ Hprev,
    bf16* __restrict__ normed) {
  __shared__ __align__(16) char sC[16384];
  __shared__ __align__(16) char sBX[16384];
  __shared__ __align__(16) char sP[32768];
  __shared__ __align__(16) char sST[8192];
  __shared__ float sdt[CHUNK], scum2[CHUNK], stot[2];
  const int chunk = blockIdx.x, h = blockIdx.y, g = h >> 2;
  const int tid = threadIdx.x, lane = tid & 63, wid = tid >> 6;
  const int t0 = chunk * CHUNK;
  const int fr = lane & 15, kq = lane >> 4;
  const int wi = wid * 32;
  // stage C,B into LDS; X into registers
  short8 rX[4];
  {
    const short* cg = (const short*)conv;
#pragma unroll
    for (int it = 0; it < 4; ++it) {
      int cid = tid + it * 256;
      int r = cid >> 3, c8 = (cid & 7) * 8;
      size_t rowoff = (size_t)(t0 + r) * CONV_DIM;
      *(short8*)swz128p(sC, r, c8) = *(const short8*)(cg + rowoff + 2 * D_XB + h * 64 + c8);
      *(short8*)swz128p(sBX, r, c8) = *(const short8*)(cg + rowoff + D_XB + g * 64 + c8);
      rX[it] = *(const short8*)(cg + rowoff + g * 64 + c8);
    }
    if (tid < CHUNK) {
      float x = dtraw[(size_t)(t0 + tid) * NHEADS + h] + dt_bias[h];
      sdt[tid] = (x > 20.f) ? x : log1pf(expf(x));
    }
  }
  __syncthreads();
  // parallel inclusive scan -> scum2
  const float Ah2 = -expf(A_log[h]) * LOG2E;
  float s_incl = 0.f;
  if (tid < CHUNK) {
    s_incl = sdt[tid] * Ah2;
#pragma unroll
    for (int off = 1; off < 64; off <<= 1) {
      float tt = __shfl_up(s_incl, off);
      if (lane >= off) s_incl += tt;
    }
    if (lane == 63) stot[wid] = s_incl;
  }
  __syncthreads();
  if (tid < CHUNK) scum2[tid] = s_incl + ((tid >= 64) ? stot[0] : 0.f);
  // G = C @ B^T (does not read scum2; scum2 visible by P-phase via later barriers)
  f32x4 accG[2][8] = {};
#pragma unroll
  for (int ks = 0; ks < 2; ++ks) {
    short8 a[2], b[8];
#pragma unroll
    for (int m = 0; m < 2; ++m)
      a[m] = *(const short8*)swz128p(sC, wi + m * 16 + fr, ks * 32 + kq * 8);
#pragma unroll
    for (int n = 0; n < 8; ++n)
      b[n] = *(const short8*)swz128p(sBX, n * 16 + fr, ks * 32 + kq * 8);
#pragma unroll
    for (int m = 0; m < 2; ++m)
#pragma unroll
      for (int n = 0; n < 8; ++n)
        accG[m][n] = __builtin_amdgcn_mfma_f32_16x16x32_bf16(a[m], b[n], accG[m][n], 0, 0, 0);
  }
  __syncthreads();
  // XT from registers into sBX (B dead); stage Hprev -> sST
  {
#pragma unroll
    for (int it = 0; it < 4; ++it) {
      int cid = tid + it * 256;
      int r = cid >> 3, c8 = (cid & 7) * 8;
#pragma unroll
      for (int q = 0; q < 8; ++q)
        *(short*)swz256p(sBX, c8 + q, r) = rX[it][q];
    }
    const short* Hp = Hprev + ((size_t)(chunk * NHEADS + h)) * (DSTATE * DSTATE);
#pragma unroll
    for (int it = 0; it < 2; ++it) {
      int cid = tid + it * 256;
      int pr = cid >> 3, c8 = (cid & 7) * 8;
      *(short8*)swz128p(sST, pr, c8) = *(const short8*)(Hp + pr * 64 + c8);
    }
  }
  __syncthreads();
#pragma unroll
  for (int m = 0; m < 2; ++m)
#pragma unroll
    for (int jj = 0; jj < 4; ++jj) {
      int i = wi + m * 16 + kq * 4 + jj;
      float ci = scum2[i];
#pragma unroll
      for (int n = 0; n < 8; ++n) {
        int j = n * 16 + fr;
        float w = (j <= i) ? exp2f(ci - scum2[j]) * sdt[j] : 0.f;
        *(short*)swz256p(sP, i, j) = f2bf(accG[m][n][jj] * w);
      }
    }
  __syncthreads();
  f32x4 acc1[2][4] = {};
#pragma unroll
  for (int ks = 0; ks < 4; ++ks) {
    short8 a[2], b[4];
#pragma unroll
    for (int m = 0; m < 2; ++m)
      a[m] = *(const short8*)swz256p(sP, wi + m * 16 + fr, ks * 32 + kq * 8);
#pragma unroll
    for (int n = 0; n < 4; ++n)
      b[n] = *(const short8*)swz256p(sBX, n * 16 + fr, ks * 32 + kq * 8);
#pragma unroll
    for (int m = 0; m < 2; ++m)
#pragma unroll
      for (int n = 0; n < 4; ++n)
        acc1[m][n] = __builtin_amdgcn_mfma_f32_16x16x32_bf16(a[m], b[n], acc1[m][n], 0, 0, 0);
  }
  f32x4 acc2[2][4] = {};
#pragma unroll
  for (int ks = 0; ks < 2; ++ks) {
    short8 a[2], b[4];
#pragma unroll
    for (int m = 0; m < 2; ++m)
      a[m] = *(const short8*)swz128p(sC, wi + m * 16 + fr, ks * 32 + kq * 8);
#pragma unroll
    for (int n = 0; n < 4; ++n)
      b[n] = *(const short8*)swz128p(sST, n * 16 + fr, ks * 32 + kq * 8);
#pragma unroll
    for (int m = 0; m < 2; ++m)
#pragma unroll
      for (int n = 0; n < 4; ++n)
        acc2[m][n] = __builtin_amdgcn_mfma_f32_16x16x32_bf16(a[m], b[n], acc2[m][n], 0, 0, 0);
  }
  const float Dh = Dv[h];
#pragma unroll
  for (int m = 0; m < 2; ++m)
#pragma unroll
    for (int jj = 0; jj < 4; ++jj) {
      int i = wi + m * 16 + kq * 4 + jj;
      int t = t0 + i;
      float e2 = exp2f(scum2[i]);
      float vs[4];
      float ss = 0.f;
#pragma unroll
      for (int n = 0; n < 4; ++n) {
        int p = n * 16 + fr;
        float xv = bf2f(((const short*)conv)[(size_t)t * CONV_DIM + g * 64 + p]);
        float zv = bf2f(((const short*)z)[(size_t)t * D_INNER + h * 64 + p]);
        float y = acc1[m][n][jj] + e2 * acc2[m][n][jj] + xv * Dh;
        float sz = zv / (1.f + expf(-zv));
        float v = y * sz;
        vs[n] = v;
        ss += v * v;
      }
      ss += __shfl_xor(ss, 1);
      ss += __shfl_xor(ss, 2);
      ss += __shfl_xor(ss, 4);
      ss += __shfl_xor(ss, 8);
      float rinv = rsqrtf(ss * (1.f / 64.f) + EPS);
#pragma unroll
      for (int n = 0; n < 4; ++n) {
        int p = n * 16 + fr;
        ((short*)normed)[(size_t)t * D_INNER + h * 64 + p] = f2bf(vs[n] * rinv * nw[h * 64 + p]);
      }
    }
}

// ---------------- launch ----------------
extern "C" void kernel_launch(void* const* d_in, const int* in_sizes, int n_in,
                              void* d_out, int out_size, void* d_ws, size_t ws_size,
                              hipStream_t stream) {
  const float* u       = (const float*)d_in[0];
  const float* W_in    = (const float*)d_in[1];
  const float* conv_w  = (const float*)d_in[2];
  const float* conv_b  = (const float*)d_in[3];
  const float* dt_bias = (const float*)d_in[4];
  const float* A_log   = (const float*)d_in[5];
  const float* Dv      = (const float*)d_in[6];
  const float* norm_w  = (const float*)d_in[7];
  const float* W_out   = (const float*)d_in[8];
  float* out = (float*)d_out;

  if (ws_size < WS_BYTES) {
    size_t n = (size_t)out_size;
    fill_kernel<<<(n + 255) / 256, 256, 0, stream>>>(out, n, 1000.0f);
    return;
  }

  char* wsb   = (char*)d_ws;
  bf16*  z    = (bf16*)(wsb);
  bf16*  raw  = (bf16*)(wsb + Z_BYTES);
  float* dtp  = (float*)(wsb + Z_BYTES + RAW_BYTES);
  float* cdec = (float*)(wsb + Z_BYTES + RAW_BYTES + DTP_BYTES);
  char*  R    = wsb + Z_BYTES + RAW_BYTES + DTP_BYTES + CDEC_BYTES;
  short* u_bf  = (short*)(R);
  short* WinT  = (short*)(R + U_BYTES);
  bf16*  conv  = (bf16*)(R);
  short* Sbuf  = (short*)(R + CONV_BYTES);
  short* WoutT = (short*)(R);
  bf16*  normed = raw;   // raw dead after conv; passC reads conv buffer only

  // 0) casts for GEMM1
  cast_f32_bf16<<<(U_BYTES / 8 + 255) / 256, 256, 0, stream>>>(u, u_bf, U_BYTES / 8);
  {
    dim3 grid(NPAD / 32, D_MODEL / 128);
    transpose_cast<<<grid, 256, 0, stream>>>(W_in, WinT, D_MODEL, D_IN_PROJ);
  }
  // 1) GEMM1 (256x256, round-7 schedule)
  gemm1_8ph<<<(NPAD / 256) * (SEQLEN / 256), 512, 0, stream>>>(u_bf, WinT, z, raw, dtp);
  // 2) conv + silu (vectorized, all channels)
  conv_silu_kernel<<<(SEQLEN * (CONV_DIM / 8) + 255) / 256, 256, 0, stream>>>(raw, conv_w, conv_b, conv);
  // 3) SSD pass A (reg-staged)
  {
    dim3 grid(NCHUNK, NHEADS);
    ssd_passA<<<grid, 256, 0, stream>>>(conv, dtp, dt_bias, A_log, Sbuf, cdec);
  }
  // 4) SSD pass B
  {
    dim3 grid(NHEADS, 4);
    ssd_passB<<<grid, 256, 0, stream>>>(Sbuf, cdec);
  }
  // 5) SSD pass C (reg-X) -> normed (aliases raw)
  {
    dim3 grid(NCHUNK, NHEADS);
    ssd_passC<<<grid, 256, 0, stream>>>(z, conv, dtp, dt_bias, A_log, Dv, norm_w, Sbuf, normed);
  }
  // 6) W_out transpose + GEMM2 (128x256)
  {
    dim3 grid(D_MODEL / 32, D_INNER / 128);
    transpose_cast<<<grid, 256, 0, stream>>>(W_out, WoutT, D_INNER, D_MODEL);
  }
  gemm2_8ph<<<(SEQLEN / 128) * (D_MODEL / 256), 512, 0, stream>>>((const short*)normed, WoutT, out);
}